// Round 11
// baseline (486.667 us; speedup 1.0000x reference)
//
#include <hip/hip_runtime.h>
#include <hip/hip_bf16.h>

#define NN   20000
#define EE   320000
#define GG   16
#define DD   256
#define HH   8
#define DHH  32
#define LLAYERS 2
#define DFF  512
#define DIN  32
#define DLAP 16
#define RSPLITS 16

typedef __attribute__((ext_vector_type(8))) short bf16x8;
typedef __attribute__((ext_vector_type(8))) unsigned short u16x8;
typedef __attribute__((ext_vector_type(4))) float f32x4;

__device__ __forceinline__ void gld_lds16(const void* g, void* l) {
  __builtin_amdgcn_global_load_lds((const __attribute__((address_space(1))) uint32_t*)g,
                                   (__attribute__((address_space(3))) uint32_t*)l, 16, 0, 0);
}

__device__ __forceinline__ float b2f(unsigned short s) {
  union { unsigned int i; float f; } u;
  u.i = ((unsigned int)s) << 16;
  return u.f;
}

__device__ __forceinline__ unsigned short f2bu(float f) {
  __hip_bfloat16 b = __float2bfloat16(f);
  return *(unsigned short*)&b;
}

// ---------------------------------------------------------------- embed (f32 + bf16 shadow)
__global__ __launch_bounds__(256) void k_embed(
    const float* __restrict__ feat, const float* __restrict__ lap,
    const float* __restrict__ sign, const float* __restrict__ Wh,
    const float* __restrict__ bh, const float* __restrict__ Wlp,
    const float* __restrict__ blp, float* __restrict__ h,
    __hip_bfloat16* __restrict__ hb) {
  int n = blockIdx.x;
  int d = threadIdx.x;
  float acc = bh[d] + blp[d];
  const float* frow = feat + (size_t)n * DIN;
  const float* lrow = lap + (size_t)n * DLAP;
#pragma unroll
  for (int k = 0; k < DIN; ++k) acc += frow[k] * Wh[k * DD + d];
#pragma unroll
  for (int k = 0; k < DLAP; ++k) acc += (lrow[k] * sign[k]) * Wlp[k * DD + d];
  h[(size_t)n * DD + d] = acc;
  hb[(size_t)n * DD + d] = __float2bfloat16(acc);
}

// ---------------------------------------------------------------- all weight transposes in one dispatch
__global__ __launch_bounds__(256) void k_wt_all(
    const float* __restrict__ Wq, const float* __restrict__ Wk,
    const float* __restrict__ Wv, const float* __restrict__ Wo,
    const float* __restrict__ W1, const float* __restrict__ W2,
    __hip_bfloat16* __restrict__ Wqt, __hip_bfloat16* __restrict__ Wkt,
    __hip_bfloat16* __restrict__ Wvt, __hip_bfloat16* __restrict__ Wot,
    __hip_bfloat16* __restrict__ W1t, __hip_bfloat16* __restrict__ W2t) {
  __shared__ float tile[32][33];
  int z = blockIdx.z;
  const float* in;
  __hip_bfloat16* out;
  int K, N, l;
  if (z < 8) {
    int widx = z >> 1;
    l = z & 1;
    K = DD; N = DD;
    in = (widx == 0) ? Wq : (widx == 1) ? Wk : (widx == 2) ? Wv : Wo;
    out = (widx == 0) ? Wqt : (widx == 1) ? Wkt : (widx == 2) ? Wvt : Wot;
  } else if (z < 10) {
    l = z - 8; K = DD; N = DFF; in = W1; out = W1t;
  } else {
    l = z - 10; K = DFF; N = DD; in = W2; out = W2t;
  }
  int bx = blockIdx.x, by = blockIdx.y;
  if (bx * 32 >= N || by * 32 >= K) return;
  const float* inl = in + (size_t)l * K * N;
  __hip_bfloat16* outl = out + (size_t)l * N * K;
  int tx = threadIdx.x & 31, ty = threadIdx.x >> 5;
#pragma unroll
  for (int i = 0; i < 32; i += 8)
    tile[ty + i][tx] = inl[(size_t)(by * 32 + ty + i) * N + bx * 32 + tx];
  __syncthreads();
#pragma unroll
  for (int i = 0; i < 32; i += 8)
    outl[(size_t)(bx * 32 + ty + i) * K + by * 32 + tx] = __float2bfloat16(tile[tx][ty + i]);
}

// ---------------------------------------------------------------- MFMA bf16 GEMM (128x128, BK=32)
// KVPACK: z=0 -> Q normal into C0; z=1 -> K dim-interleaved into C1; z=2 -> V dim-interleaved into C1.
template <bool BIAS, bool RELU, bool KVPACK>
__global__ __launch_bounds__(256) void gemm_mfma(
    const __hip_bfloat16* __restrict__ A,
    const __hip_bfloat16* __restrict__ Bt0, const __hip_bfloat16* __restrict__ Bt1,
    const __hip_bfloat16* __restrict__ Bt2,
    const float* __restrict__ bias,
    __hip_bfloat16* __restrict__ C0, __hip_bfloat16* __restrict__ C1,
    int M, int K, int ldc0) {
  const __hip_bfloat16* Bt = (blockIdx.z == 0) ? Bt0 : (blockIdx.z == 1) ? Bt1 : Bt2;
  __hip_bfloat16* Cout = (blockIdx.z == 0) ? C0 : C1;
  const int vo = (blockIdx.z == 2) ? 4 : 0;

  __shared__ short lA[2][4][128][8];
  __shared__ short lB[2][4][128][8];

  const int t = threadIdx.x;
  const int lane = t & 63, w = t >> 6;
  const int bm = blockIdx.x * 128, bn = blockIdx.y * 128;
  const int wr = w >> 1, wc = w & 1;
  const int fr = lane & 15, fg = lane >> 4;

  f32x4 acc[4][4] = {};

  auto stage = [&](int buf, int kt) {
    const int k0 = kt * 32;
#pragma unroll
    for (int it = 0; it < 2; ++it) {
      const int cbase = it * 256 + w * 64;
      const int c = cbase + lane;
      const int g = c >> 7, r = c & 127;
      int arow = bm + r;
      if (arow >= M) arow = M - 1;
      gld_lds16(A + (size_t)arow * K + k0 + g * 8,
                (short*)lA + ((size_t)buf * 512 + cbase) * 8);
      gld_lds16(Bt + (size_t)(bn + r) * K + k0 + g * 8,
                (short*)lB + ((size_t)buf * 512 + cbase) * 8);
    }
  };

  const int nt = K >> 5;
  stage(0, 0);
  for (int kt = 0; kt < nt; ++kt) {
    const int buf = kt & 1;
    __syncthreads();
    if (kt + 1 < nt) stage(buf ^ 1, kt + 1);
    bf16x8 af[4], bfr[4];
#pragma unroll
    for (int i = 0; i < 4; ++i)
      af[i] = *(const bf16x8*)&lA[buf][fg][wr * 64 + i * 16 + fr][0];
#pragma unroll
    for (int j = 0; j < 4; ++j)
      bfr[j] = *(const bf16x8*)&lB[buf][fg][wc * 64 + j * 16 + fr][0];
#pragma unroll
    for (int i = 0; i < 4; ++i)
#pragma unroll
      for (int j = 0; j < 4; ++j)
        acc[i][j] = __builtin_amdgcn_mfma_f32_16x16x32_bf16(af[i], bfr[j], acc[i][j], 0, 0, 0);
  }

#pragma unroll
  for (int i = 0; i < 4; ++i) {
    const int row0 = bm + wr * 64 + i * 16 + fg * 4;
#pragma unroll
    for (int j = 0; j < 4; ++j) {
      const int col = bn + wc * 64 + j * 16 + fr;
      float bv = BIAS ? bias[col] : 0.f;
#pragma unroll
      for (int r = 0; r < 4; ++r) {
        const int row = row0 + r;
        if (row >= M) continue;
        float v = acc[i][j][r] + bv;
        if (RELU) v = fmaxf(v, 0.f);
        if (KVPACK && blockIdx.z != 0) {
          Cout[(size_t)row * (2 * DD) + ((col >> 2) << 3) + vo + (col & 3)] =
              __float2bfloat16(v);
        } else {
          Cout[(size_t)row * ldc0 + col] = __float2bfloat16(v);
        }
      }
    }
  }
}

// ---------------------------------------------------------------- LDS-free GEMM (16x256) + bias + residual + LayerNorm
// 256 thr = 4 waves; wave w owns cols [w*64, w*64+64); all waves share 16 rows.
// A/B fragments loaded DIRECTLY from global in MFMA layout - no LDS staging, no k-loop barriers.
// grid = M/16 = 1250 blocks -> ~5 waves/SIMD for latency hiding.
template <int KK>
__global__ __launch_bounds__(256) void gemm_ln(
    const __hip_bfloat16* __restrict__ A,     // [M][KK]
    const __hip_bfloat16* __restrict__ Bt,    // [256][KK]
    const float* __restrict__ bias,           // [256]
    float* __restrict__ h,                    // residual in / LN out (f32)
    __hip_bfloat16* __restrict__ hb,          // LN out (bf16 shadow)
    const float* __restrict__ g, const float* __restrict__ b,
    int M) {
  __shared__ float redS[16];
  __shared__ float redQ[16];

  const int t = threadIdx.x;
  const int lane = t & 63, w = t >> 6;
  const int bm = blockIdx.x * 16;
  const int fr = lane & 15, fg = lane >> 4;

  if (t < 16) { redS[t] = 0.f; redQ[t] = 0.f; }

  f32x4 acc[4] = {};
  const __hip_bfloat16* ap = A + (size_t)(bm + fr) * KK + fg * 8;
  const __hip_bfloat16* bp = Bt + (size_t)(w * 64 + fr) * KK + fg * 8;

#pragma unroll 4
  for (int kt = 0; kt < KK / 32; ++kt) {
    const int k0 = kt * 32;
    bf16x8 af = *(const bf16x8*)(ap + k0);
    bf16x8 bfr[4];
#pragma unroll
    for (int j = 0; j < 4; ++j)
      bfr[j] = *(const bf16x8*)(bp + (size_t)j * 16 * KK + k0);
#pragma unroll
    for (int j = 0; j < 4; ++j)
      acc[j] = __builtin_amdgcn_mfma_f32_16x16x32_bf16(af, bfr[j], acc[j], 0, 0, 0);
  }

  __syncthreads();  // redS/redQ init visible
  // pass 1: x = gemm + bias + residual (overwrite acc); row sum/sumsq into LDS
#pragma unroll
  for (int r = 0; r < 4; ++r) {
    const int lrow = fg * 4 + r;
    const int grow = bm + lrow;
    float s = 0.f, q = 0.f;
#pragma unroll
    for (int j = 0; j < 4; ++j) {
      const int col = w * 64 + j * 16 + fr;
      float x = acc[j][r] + bias[col] + h[(size_t)grow * DD + col];
      acc[j][r] = x;
      s += x;
      q += x * x;
    }
#pragma unroll
    for (int o = 1; o < 16; o <<= 1) {
      s += __shfl_xor(s, o);
      q += __shfl_xor(q, o);
    }
    if (fr == 0) {
      atomicAdd(&redS[lrow], s);
      atomicAdd(&redQ[lrow], q);
    }
  }
  __syncthreads();
  // pass 2: normalize
#pragma unroll
  for (int r = 0; r < 4; ++r) {
    const int lrow = fg * 4 + r;
    const int grow = bm + lrow;
    const float mean = redS[lrow] * (1.f / 256.f);
    const float var = redQ[lrow] * (1.f / 256.f) - mean * mean;
    const float rs = rsqrtf(var + 1e-5f);
#pragma unroll
    for (int j = 0; j < 4; ++j) {
      const int col = w * 64 + j * 16 + fr;
      float v = g[col] * ((acc[j][r] - mean) * rs) + b[col];
      h[(size_t)grow * DD + col] = v;
      hb[(size_t)grow * DD + col] = __float2bfloat16(v);
    }
  }
}

// ---------------------------------------------------------------- CSR build
__global__ void k_hist(const int* __restrict__ dst, int* __restrict__ deg, int n) {
  int i = blockIdx.x * blockDim.x + threadIdx.x;
  if (i < n) atomicAdd(&deg[dst[i]], 1);
}

__global__ __launch_bounds__(256) void k_scan_block(
    const int* __restrict__ in, int* __restrict__ ex, int* __restrict__ bsum, int n) {
  __shared__ int sm[256];
  int t = threadIdx.x;
  int i = blockIdx.x * 256 + t;
  int v = (i < n) ? in[i] : 0;
  sm[t] = v;
  __syncthreads();
  for (int o = 1; o < 256; o <<= 1) {
    int x = (t >= o) ? sm[t - o] : 0;
    __syncthreads();
    sm[t] += x;
    __syncthreads();
  }
  if (i < n) ex[i] = sm[t] - v;
  if (t == 255) bsum[blockIdx.x] = sm[255];
}

__global__ __launch_bounds__(256) void k_scan_top(
    const int* __restrict__ bsum, int* __restrict__ boff, int nb) {
  __shared__ int sm[256];
  int t = threadIdx.x;
  int v = (t < nb) ? bsum[t] : 0;
  sm[t] = v;
  __syncthreads();
  for (int o = 1; o < 256; o <<= 1) {
    int x = (t >= o) ? sm[t - o] : 0;
    __syncthreads();
    sm[t] += x;
    __syncthreads();
  }
  if (t < nb) boff[t] = sm[t] - v;
}

__global__ void k_finish_indptr(const int* __restrict__ ex, const int* __restrict__ boff,
                                int* __restrict__ indptr, int* __restrict__ cursor,
                                int n, int total) {
  int i = blockIdx.x * 256 + threadIdx.x;
  if (i < n) {
    int v = ex[i] + boff[i >> 8];
    indptr[i] = v;
    cursor[i] = v;
  }
  if (i == 0) indptr[n] = total;
}

__global__ void k_fill(const int* __restrict__ dst, const int* __restrict__ src,
                       int* __restrict__ cursor, int* __restrict__ csr_src, int n) {
  int i = blockIdx.x * blockDim.x + threadIdx.x;
  if (i < n) {
    int pos = atomicAdd(&cursor[dst[i]], 1);
    csr_src[pos] = src[i];
  }
}

// graph boundaries from sorted gids
__global__ void k_bounds(const int* __restrict__ gid, int* __restrict__ gb, int n) {
  int i = blockIdx.x * blockDim.x + threadIdx.x;
  if (i >= n) return;
  int g = gid[i];
  if (i == 0) {
    for (int x = 0; x <= g; ++x) gb[x] = 0;
  } else {
    int pg = gid[i - 1];
    for (int x = pg + 1; x <= g; ++x) gb[x] = i;
  }
  if (i == n - 1) {
    for (int x = g + 1; x <= GG; ++x) gb[x] = n;
  }
}

// ---------------------------------------------------------------- fused attention: half-wave per edge
__global__ __launch_bounds__(256) void k_attn(
    const int* __restrict__ indptr, const int* __restrict__ csr_src,
    const __hip_bfloat16* __restrict__ Q, const __hip_bfloat16* __restrict__ kvb,
    __hip_bfloat16* __restrict__ attn) {
  int n = blockIdx.x * 4 + (threadIdx.x >> 6);
  if (n >= NN) return;
  int lane = threadIdx.x & 63;
  int half = lane >> 5;
  int sl = lane & 31;
  int doff = sl * 8;
  int s0 = indptr[n], s1 = indptr[n + 1];

  u16x8 qv = *(const u16x8*)((const unsigned short*)Q + (size_t)n * DD + doff);
  float q[8];
#pragma unroll
  for (int i = 0; i < 8; ++i) q[i] = b2f((unsigned short)qv[i]);

  const unsigned short* kvp = (const unsigned short*)kvb;

  float m = 0.f, den = 0.f;
  float a[8] = {};
  int j = s0 + half;
  if (j < s1) {
    const unsigned short* row = kvp + (size_t)csr_src[j] * (2 * DD) + sl * 16;
    u16x8 c0 = *(const u16x8*)row;
    u16x8 c1 = *(const u16x8*)(row + 8);
    for (; j < s1; j += 2) {
      int jn = (j + 2 < s1) ? j + 2 : j;
      const unsigned short* rown = kvp + (size_t)csr_src[jn] * (2 * DD) + sl * 16;
      u16x8 n0 = *(const u16x8*)rown;
      u16x8 n1 = *(const u16x8*)(rown + 8);

      float dot = q[0] * b2f((unsigned short)c0[0]) + q[1] * b2f((unsigned short)c0[1]) +
                  q[2] * b2f((unsigned short)c0[2]) + q[3] * b2f((unsigned short)c0[3]) +
                  q[4] * b2f((unsigned short)c1[0]) + q[5] * b2f((unsigned short)c1[1]) +
                  q[6] * b2f((unsigned short)c1[2]) + q[7] * b2f((unsigned short)c1[3]);
      dot += __shfl_xor(dot, 1);
      dot += __shfl_xor(dot, 2);  // 4-lane head group complete
      float x = fminf(fmaxf(dot * 0.17677669529663687f, -5.f), 5.f);
      float s = __expf(x);
      if (s - m > 8.f) {
        float r = __expf(m - s);
        den *= r;
#pragma unroll
        for (int i = 0; i < 8; ++i) a[i] *= r;
        m = s;
      }
      float p = __expf(s - m);
      den += p;
      a[0] += p * b2f((unsigned short)c0[4]);
      a[1] += p * b2f((unsigned short)c0[5]);
      a[2] += p * b2f((unsigned short)c0[6]);
      a[3] += p * b2f((unsigned short)c0[7]);
      a[4] += p * b2f((unsigned short)c1[4]);
      a[5] += p * b2f((unsigned short)c1[5]);
      a[6] += p * b2f((unsigned short)c1[6]);
      a[7] += p * b2f((unsigned short)c1[7]);
      c0 = n0;
      c1 = n1;
    }
  }

  float mo = __shfl_xor(m, 32);
  float M = fmaxf(m, mo);
  float r = __expf(m - M);
  den *= r;
#pragma unroll
  for (int i = 0; i < 8; ++i) a[i] *= r;
  den += __shfl_xor(den, 32);
#pragma unroll
  for (int i = 0; i < 8; ++i) a[i] += __shfl_xor(a[i], 32);

  if (half == 0) {
    float inv = 1.f / (den > 0.f ? den : 1.f);
    u16x8 o;
#pragma unroll
    for (int i = 0; i < 8; ++i) o[i] = f2bu(a[i] * inv);
    *(u16x8*)((unsigned short*)attn + (size_t)n * DD + doff) = o;
  }
}

// ---------------------------------------------------------------- readout
__global__ __launch_bounds__(256) void k_gmean(
    const float* __restrict__ h, const int* __restrict__ gb,
    float* __restrict__ gsum) {
  int g = blockIdx.x, s = blockIdx.y;
  int t = threadIdx.x;
  int r0 = gb[g], r1 = gb[g + 1];
  int len = r1 - r0;
  int per = (len + RSPLITS - 1) / RSPLITS;
  int a = r0 + s * per;
  int b = min(r1, a + per);
  if (a >= b) return;
  float acc = 0.f;
  for (int r = a; r < b; ++r) acc += h[(size_t)r * DD + t];
  atomicAdd(&gsum[g * DD + t], acc);
}

__global__ void k_final(const float* __restrict__ gsum, const int* __restrict__ gb,
                        float* __restrict__ out) {
  int g = blockIdx.x, t = threadIdx.x;
  int len = gb[g + 1] - gb[g];
  out[g * DD + t] = gsum[g * DD + t] / (len > 0 ? (float)len : 1.f);
}

// ---------------------------------------------------------------- launch
extern "C" void kernel_launch(void* const* d_in, const int* in_sizes, int n_in,
                              void* d_out, int out_size, void* d_ws, size_t ws_size,
                              hipStream_t stream) {
  const float* feat = (const float*)d_in[0];
  const float* lap  = (const float*)d_in[1];
  const float* sign = (const float*)d_in[2];
  const int* srcs   = (const int*)d_in[3];
  const int* dsts   = (const int*)d_in[4];
  const int* gids   = (const int*)d_in[5];
  const float* Wh   = (const float*)d_in[6];
  const float* bh   = (const float*)d_in[7];
  const float* Wlp  = (const float*)d_in[8];
  const float* blp  = (const float*)d_in[9];
  const float* Wq   = (const float*)d_in[10];
  const float* Wk   = (const float*)d_in[11];
  const float* Wv   = (const float*)d_in[12];
  const float* Wo   = (const float*)d_in[13];
  const float* bo   = (const float*)d_in[14];
  const float* g1   = (const float*)d_in[15];
  const float* b1   = (const float*)d_in[16];
  const float* W1   = (const float*)d_in[17];
  const float* c1   = (const float*)d_in[18];
  const float* W2   = (const float*)d_in[19];
  const float* c2   = (const float*)d_in[20];
  const float* g2   = (const float*)d_in[21];
  const float* b2   = (const float*)d_in[22];

  char* base = (char*)d_ws;
  size_t off = 0;
  auto take = [&](size_t bytes) -> void* {
    void* p = base + off;
    off += (bytes + 255) & ~(size_t)255;
    return p;
  };
  float* h      = (float*)take((size_t)NN * DD * 4);
  __hip_bfloat16* hb  = (__hip_bfloat16*)take((size_t)NN * DD * 2);
  __hip_bfloat16* Qb  = (__hip_bfloat16*)take((size_t)NN * DD * 2);
  __hip_bfloat16* kvb = (__hip_bfloat16*)take((size_t)NN * 2 * DD * 2);
  __hip_bfloat16* t1b = (__hip_bfloat16*)take((size_t)NN * DFF * 2);
  __hip_bfloat16* Wqt = (__hip_bfloat16*)take((size_t)LLAYERS * DD * DD * 2);
  __hip_bfloat16* Wkt = (__hip_bfloat16*)take((size_t)LLAYERS * DD * DD * 2);
  __hip_bfloat16* Wvt = (__hip_bfloat16*)take((size_t)LLAYERS * DD * DD * 2);
  __hip_bfloat16* Wot = (__hip_bfloat16*)take((size_t)LLAYERS * DD * DD * 2);
  __hip_bfloat16* W1t = (__hip_bfloat16*)take((size_t)LLAYERS * DD * DFF * 2);
  __hip_bfloat16* W2t = (__hip_bfloat16*)take((size_t)LLAYERS * DFF * DD * 2);
  int* deg     = (int*)take((size_t)NN * 4);
  int* ex      = (int*)take((size_t)NN * 4);
  int* bsum    = (int*)take(256 * 4);
  int* boff    = (int*)take(256 * 4);
  int* indptr  = (int*)take((size_t)(NN + 1) * 4);
  int* cursor  = (int*)take((size_t)NN * 4);
  int* csr_src = (int*)take((size_t)EE * 4);
  int* gb      = (int*)take((size_t)(GG + 1) * 4);
  float* gsum  = (float*)take((size_t)GG * DD * 4);
  __hip_bfloat16* attnb = Qb;  // Q dead after k_attn (own-row read-before-write)

  const int NB = (NN + 255) / 256;

  // all weight transposes in one dispatch
  k_wt_all<<<dim3(DFF / 32, DFF / 32, 12), 256, 0, stream>>>(
      Wq, Wk, Wv, Wo, W1, W2, Wqt, Wkt, Wvt, Wot, W1t, W2t);

  // CSR by dst + graph bounds
  hipMemsetAsync(deg, 0, (size_t)NN * 4, stream);
  k_hist<<<(EE + 255) / 256, 256, 0, stream>>>(dsts, deg, EE);
  k_scan_block<<<NB, 256, 0, stream>>>(deg, ex, bsum, NN);
  k_scan_top<<<1, 256, 0, stream>>>(bsum, boff, NB);
  k_finish_indptr<<<NB, 256, 0, stream>>>(ex, boff, indptr, cursor, NN, EE);
  k_fill<<<(EE + 255) / 256, 256, 0, stream>>>(dsts, srcs, cursor, csr_src, EE);
  k_bounds<<<NB, 256, 0, stream>>>(gids, gb, NN);

  // embedding
  k_embed<<<NN, 256, 0, stream>>>(feat, lap, sign, Wh, bh, Wlp, blp, h, hb);

  const int MB = (NN + 127) / 128;   // 157
  const int MB16 = (NN + 15) / 16;   // 1250
  dim3 gQKV(MB, DD / 128, 3);
  dim3 gF(MB, DFF / 128, 1);

  for (int l = 0; l < LLAYERS; ++l) {
    const __hip_bfloat16* Wqt_l = Wqt + (size_t)l * DD * DD;
    const __hip_bfloat16* Wkt_l = Wkt + (size_t)l * DD * DD;
    const __hip_bfloat16* Wvt_l = Wvt + (size_t)l * DD * DD;
    const __hip_bfloat16* Wot_l = Wot + (size_t)l * DD * DD;
    const __hip_bfloat16* W1t_l = W1t + (size_t)l * DD * DFF;
    const __hip_bfloat16* W2t_l = W2t + (size_t)l * DFF * DD;
    const float* bo_l = bo + (size_t)l * DD;
    const float* g1_l = g1 + (size_t)l * DD;
    const float* b1_l = b1 + (size_t)l * DD;
    const float* c1_l = c1 + (size_t)l * DFF;
    const float* c2_l = c2 + (size_t)l * DD;
    const float* g2_l = g2 + (size_t)l * DD;
    const float* b2_l = b2 + (size_t)l * DD;

    // Q -> Qb; K,V -> kvb dim-interleaved
    gemm_mfma<false, false, true><<<gQKV, 256, 0, stream>>>(
        hb, Wqt_l, Wkt_l, Wvt_l, nullptr, Qb, kvb, NN, DD, DD);

    k_attn<<<(NN + 3) / 4, 256, 0, stream>>>(indptr, csr_src, Qb, kvb, attnb);

    gemm_ln<DD><<<MB16, 256, 0, stream>>>(attnb, Wot_l, bo_l, h, hb, g1_l, b1_l, NN);

    gemm_mfma<true, true, false><<<gF, 256, 0, stream>>>(
        hb, W1t_l, W1t_l, W1t_l, c1_l, t1b, t1b, NN, DD, DFF);

    gemm_ln<DFF><<<MB16, 256, 0, stream>>>(t1b, W2t_l, c2_l, h, hb, g2_l, b2_l, NN);
  }

  hipMemsetAsync(gsum, 0, (size_t)GG * DD * 4, stream);
  k_gmean<<<dim3(GG, RSPLITS), 256, 0, stream>>>(h, gb, gsum);
  k_final<<<GG, 256, 0, stream>>>(gsum, gb, (float*)d_out);
}

// Round 12
// 464.018 us; speedup vs baseline: 1.0488x; 1.0488x over previous
//
#include <hip/hip_runtime.h>
#include <hip/hip_bf16.h>

#define NN   20000
#define EE   320000
#define GG   16
#define DD   256
#define HH   8
#define DHH  32
#define LLAYERS 2
#define DFF  512
#define DIN  32
#define DLAP 16
#define RSPLITS 16

typedef __attribute__((ext_vector_type(8))) short bf16x8;
typedef __attribute__((ext_vector_type(8))) unsigned short u16x8;
typedef __attribute__((ext_vector_type(4))) float f32x4;

__device__ __forceinline__ void gld_lds16(const void* g, void* l) {
  __builtin_amdgcn_global_load_lds((const __attribute__((address_space(1))) uint32_t*)g,
                                   (__attribute__((address_space(3))) uint32_t*)l, 16, 0, 0);
}

__device__ __forceinline__ float b2f(unsigned short s) {
  union { unsigned int i; float f; } u;
  u.i = ((unsigned int)s) << 16;
  return u.f;
}

__device__ __forceinline__ unsigned short f2bu(float f) {
  __hip_bfloat16 b = __float2bfloat16(f);
  return *(unsigned short*)&b;
}

// ---------------------------------------------------------------- embed (f32 + bf16 shadow)
__global__ __launch_bounds__(256) void k_embed(
    const float* __restrict__ feat, const float* __restrict__ lap,
    const float* __restrict__ sign, const float* __restrict__ Wh,
    const float* __restrict__ bh, const float* __restrict__ Wlp,
    const float* __restrict__ blp, float* __restrict__ h,
    __hip_bfloat16* __restrict__ hb) {
  int n = blockIdx.x;
  int d = threadIdx.x;
  float acc = bh[d] + blp[d];
  const float* frow = feat + (size_t)n * DIN;
  const float* lrow = lap + (size_t)n * DLAP;
#pragma unroll
  for (int k = 0; k < DIN; ++k) acc += frow[k] * Wh[k * DD + d];
#pragma unroll
  for (int k = 0; k < DLAP; ++k) acc += (lrow[k] * sign[k]) * Wlp[k * DD + d];
  h[(size_t)n * DD + d] = acc;
  hb[(size_t)n * DD + d] = __float2bfloat16(acc);
}

// ---------------------------------------------------------------- all weight transposes in one dispatch
__global__ __launch_bounds__(256) void k_wt_all(
    const float* __restrict__ Wq, const float* __restrict__ Wk,
    const float* __restrict__ Wv, const float* __restrict__ Wo,
    const float* __restrict__ W1, const float* __restrict__ W2,
    __hip_bfloat16* __restrict__ Wqt, __hip_bfloat16* __restrict__ Wkt,
    __hip_bfloat16* __restrict__ Wvt, __hip_bfloat16* __restrict__ Wot,
    __hip_bfloat16* __restrict__ W1t, __hip_bfloat16* __restrict__ W2t) {
  __shared__ float tile[32][33];
  int z = blockIdx.z;
  const float* in;
  __hip_bfloat16* out;
  int K, N, l;
  if (z < 8) {
    int widx = z >> 1;
    l = z & 1;
    K = DD; N = DD;
    in = (widx == 0) ? Wq : (widx == 1) ? Wk : (widx == 2) ? Wv : Wo;
    out = (widx == 0) ? Wqt : (widx == 1) ? Wkt : (widx == 2) ? Wvt : Wot;
  } else if (z < 10) {
    l = z - 8; K = DD; N = DFF; in = W1; out = W1t;
  } else {
    l = z - 10; K = DFF; N = DD; in = W2; out = W2t;
  }
  int bx = blockIdx.x, by = blockIdx.y;
  if (bx * 32 >= N || by * 32 >= K) return;
  const float* inl = in + (size_t)l * K * N;
  __hip_bfloat16* outl = out + (size_t)l * N * K;
  int tx = threadIdx.x & 31, ty = threadIdx.x >> 5;
#pragma unroll
  for (int i = 0; i < 32; i += 8)
    tile[ty + i][tx] = inl[(size_t)(by * 32 + ty + i) * N + bx * 32 + tx];
  __syncthreads();
#pragma unroll
  for (int i = 0; i < 32; i += 8)
    outl[(size_t)(bx * 32 + ty + i) * K + by * 32 + tx] = __float2bfloat16(tile[tx][ty + i]);
}

// ---------------------------------------------------------------- MFMA bf16 GEMM (128x128, BK=32)
// KVPACK: z=0 -> Q into C0; z=1 -> K dim-interleaved into C1; z=2 -> V dim-interleaved into C1.
// OUTF32: C0 is float* (full-precision output for LN input).
template <bool BIAS, bool RELU, bool KVPACK, bool OUTF32>
__global__ __launch_bounds__(256) void gemm_mfma(
    const __hip_bfloat16* __restrict__ A,
    const __hip_bfloat16* __restrict__ Bt0, const __hip_bfloat16* __restrict__ Bt1,
    const __hip_bfloat16* __restrict__ Bt2,
    const float* __restrict__ bias,
    void* __restrict__ C0, void* __restrict__ C1,
    int M, int K, int ldc0) {
  const __hip_bfloat16* Bt = (blockIdx.z == 0) ? Bt0 : (blockIdx.z == 1) ? Bt1 : Bt2;
  void* Cout = (blockIdx.z == 0) ? C0 : C1;
  const int vo = (blockIdx.z == 2) ? 4 : 0;

  __shared__ short lA[2][4][128][8];
  __shared__ short lB[2][4][128][8];

  const int t = threadIdx.x;
  const int lane = t & 63, w = t >> 6;
  const int bm = blockIdx.x * 128, bn = blockIdx.y * 128;
  const int wr = w >> 1, wc = w & 1;
  const int fr = lane & 15, fg = lane >> 4;

  f32x4 acc[4][4] = {};

  auto stage = [&](int buf, int kt) {
    const int k0 = kt * 32;
#pragma unroll
    for (int it = 0; it < 2; ++it) {
      const int cbase = it * 256 + w * 64;
      const int c = cbase + lane;
      const int g = c >> 7, r = c & 127;
      int arow = bm + r;
      if (arow >= M) arow = M - 1;
      gld_lds16(A + (size_t)arow * K + k0 + g * 8,
                (short*)lA + ((size_t)buf * 512 + cbase) * 8);
      gld_lds16(Bt + (size_t)(bn + r) * K + k0 + g * 8,
                (short*)lB + ((size_t)buf * 512 + cbase) * 8);
    }
  };

  const int nt = K >> 5;
  stage(0, 0);
  for (int kt = 0; kt < nt; ++kt) {
    const int buf = kt & 1;
    __syncthreads();
    if (kt + 1 < nt) stage(buf ^ 1, kt + 1);
    bf16x8 af[4], bfr[4];
#pragma unroll
    for (int i = 0; i < 4; ++i)
      af[i] = *(const bf16x8*)&lA[buf][fg][wr * 64 + i * 16 + fr][0];
#pragma unroll
    for (int j = 0; j < 4; ++j)
      bfr[j] = *(const bf16x8*)&lB[buf][fg][wc * 64 + j * 16 + fr][0];
#pragma unroll
    for (int i = 0; i < 4; ++i)
#pragma unroll
      for (int j = 0; j < 4; ++j)
        acc[i][j] = __builtin_amdgcn_mfma_f32_16x16x32_bf16(af[i], bfr[j], acc[i][j], 0, 0, 0);
  }

#pragma unroll
  for (int i = 0; i < 4; ++i) {
    const int row0 = bm + wr * 64 + i * 16 + fg * 4;
#pragma unroll
    for (int j = 0; j < 4; ++j) {
      const int col = bn + wc * 64 + j * 16 + fr;
      float bv = BIAS ? bias[col] : 0.f;
#pragma unroll
      for (int r = 0; r < 4; ++r) {
        const int row = row0 + r;
        if (row >= M) continue;
        float v = acc[i][j][r] + bv;
        if (RELU) v = fmaxf(v, 0.f);
        if (KVPACK && blockIdx.z != 0) {
          ((__hip_bfloat16*)Cout)[(size_t)row * (2 * DD) + ((col >> 2) << 3) + vo + (col & 3)] =
              __float2bfloat16(v);
        } else if (OUTF32) {
          ((float*)Cout)[(size_t)row * ldc0 + col] = v;
        } else {
          ((__hip_bfloat16*)Cout)[(size_t)row * ldc0 + col] = __float2bfloat16(v);
        }
      }
    }
  }
}

// ---------------------------------------------------------------- residual + LayerNorm (in-place on h, bf16 shadow)
__global__ __launch_bounds__(256) void k_ln(
    float* __restrict__ h, const float* __restrict__ add,
    const float* __restrict__ g, const float* __restrict__ b,
    __hip_bfloat16* __restrict__ hb, int n) {
  int row = blockIdx.x * 4 + (threadIdx.x >> 6);
  int lane = threadIdx.x & 63;
  if (row >= n) return;
  const size_t base = (size_t)row * DD;
  float x[4];
  float s = 0.f;
#pragma unroll
  for (int j = 0; j < 4; ++j) {
    int d = lane + j * 64;
    x[j] = h[base + d] + add[base + d];
    s += x[j];
  }
#pragma unroll
  for (int o = 32; o > 0; o >>= 1) s += __shfl_xor(s, o, 64);
  float mean = s * (1.f / 256.f);
  float vs = 0.f;
#pragma unroll
  for (int j = 0; j < 4; ++j) {
    float d = x[j] - mean;
    vs += d * d;
  }
#pragma unroll
  for (int o = 32; o > 0; o >>= 1) vs += __shfl_xor(vs, o, 64);
  float rs = rsqrtf(vs * (1.f / 256.f) + 1e-5f);
#pragma unroll
  for (int j = 0; j < 4; ++j) {
    int d = lane + j * 64;
    float v = g[d] * ((x[j] - mean) * rs) + b[d];
    h[base + d] = v;
    hb[base + d] = __float2bfloat16(v);
  }
}

// ---------------------------------------------------------------- CSR build
__global__ void k_hist(const int* __restrict__ dst, int* __restrict__ deg, int n) {
  int i = blockIdx.x * blockDim.x + threadIdx.x;
  if (i < n) atomicAdd(&deg[dst[i]], 1);
}

__global__ __launch_bounds__(256) void k_scan_block(
    const int* __restrict__ in, int* __restrict__ ex, int* __restrict__ bsum, int n) {
  __shared__ int sm[256];
  int t = threadIdx.x;
  int i = blockIdx.x * 256 + t;
  int v = (i < n) ? in[i] : 0;
  sm[t] = v;
  __syncthreads();
  for (int o = 1; o < 256; o <<= 1) {
    int x = (t >= o) ? sm[t - o] : 0;
    __syncthreads();
    sm[t] += x;
    __syncthreads();
  }
  if (i < n) ex[i] = sm[t] - v;
  if (t == 255) bsum[blockIdx.x] = sm[255];
}

__global__ __launch_bounds__(256) void k_scan_top(
    const int* __restrict__ bsum, int* __restrict__ boff, int nb) {
  __shared__ int sm[256];
  int t = threadIdx.x;
  int v = (t < nb) ? bsum[t] : 0;
  sm[t] = v;
  __syncthreads();
  for (int o = 1; o < 256; o <<= 1) {
    int x = (t >= o) ? sm[t - o] : 0;
    __syncthreads();
    sm[t] += x;
    __syncthreads();
  }
  if (t < nb) boff[t] = sm[t] - v;
}

__global__ void k_finish_indptr(const int* __restrict__ ex, const int* __restrict__ boff,
                                int* __restrict__ indptr, int* __restrict__ cursor,
                                int n, int total) {
  int i = blockIdx.x * 256 + threadIdx.x;
  if (i < n) {
    int v = ex[i] + boff[i >> 8];
    indptr[i] = v;
    cursor[i] = v;
  }
  if (i == 0) indptr[n] = total;
}

__global__ void k_fill(const int* __restrict__ dst, const int* __restrict__ src,
                       int* __restrict__ cursor, int* __restrict__ csr_src, int n) {
  int i = blockIdx.x * blockDim.x + threadIdx.x;
  if (i < n) {
    int pos = atomicAdd(&cursor[dst[i]], 1);
    csr_src[pos] = src[i];
  }
}

// graph boundaries from sorted gids
__global__ void k_bounds(const int* __restrict__ gid, int* __restrict__ gb, int n) {
  int i = blockIdx.x * blockDim.x + threadIdx.x;
  if (i >= n) return;
  int g = gid[i];
  if (i == 0) {
    for (int x = 0; x <= g; ++x) gb[x] = 0;
  } else {
    int pg = gid[i - 1];
    for (int x = pg + 1; x <= g; ++x) gb[x] = i;
  }
  if (i == n - 1) {
    for (int x = g + 1; x <= GG; ++x) gb[x] = n;
  }
}

// ---------------------------------------------------------------- fused attention: half-wave per edge
__global__ __launch_bounds__(256) void k_attn(
    const int* __restrict__ indptr, const int* __restrict__ csr_src,
    const __hip_bfloat16* __restrict__ Q, const __hip_bfloat16* __restrict__ kvb,
    __hip_bfloat16* __restrict__ attn) {
  int n = blockIdx.x * 4 + (threadIdx.x >> 6);
  if (n >= NN) return;
  int lane = threadIdx.x & 63;
  int half = lane >> 5;
  int sl = lane & 31;
  int doff = sl * 8;
  int s0 = indptr[n], s1 = indptr[n + 1];

  u16x8 qv = *(const u16x8*)((const unsigned short*)Q + (size_t)n * DD + doff);
  float q[8];
#pragma unroll
  for (int i = 0; i < 8; ++i) q[i] = b2f((unsigned short)qv[i]);

  const unsigned short* kvp = (const unsigned short*)kvb;

  float m = 0.f, den = 0.f;
  float a[8] = {};
  int j = s0 + half;
  if (j < s1) {
    const unsigned short* row = kvp + (size_t)csr_src[j] * (2 * DD) + sl * 16;
    u16x8 c0 = *(const u16x8*)row;
    u16x8 c1 = *(const u16x8*)(row + 8);
    for (; j < s1; j += 2) {
      int jn = (j + 2 < s1) ? j + 2 : j;
      const unsigned short* rown = kvp + (size_t)csr_src[jn] * (2 * DD) + sl * 16;
      u16x8 n0 = *(const u16x8*)rown;
      u16x8 n1 = *(const u16x8*)(rown + 8);

      float dot = q[0] * b2f((unsigned short)c0[0]) + q[1] * b2f((unsigned short)c0[1]) +
                  q[2] * b2f((unsigned short)c0[2]) + q[3] * b2f((unsigned short)c0[3]) +
                  q[4] * b2f((unsigned short)c1[0]) + q[5] * b2f((unsigned short)c1[1]) +
                  q[6] * b2f((unsigned short)c1[2]) + q[7] * b2f((unsigned short)c1[3]);
      dot += __shfl_xor(dot, 1);
      dot += __shfl_xor(dot, 2);  // 4-lane head group complete
      float x = fminf(fmaxf(dot * 0.17677669529663687f, -5.f), 5.f);
      float s = __expf(x);
      if (s - m > 8.f) {
        float r = __expf(m - s);
        den *= r;
#pragma unroll
        for (int i = 0; i < 8; ++i) a[i] *= r;
        m = s;
      }
      float p = __expf(s - m);
      den += p;
      a[0] += p * b2f((unsigned short)c0[4]);
      a[1] += p * b2f((unsigned short)c0[5]);
      a[2] += p * b2f((unsigned short)c0[6]);
      a[3] += p * b2f((unsigned short)c0[7]);
      a[4] += p * b2f((unsigned short)c1[4]);
      a[5] += p * b2f((unsigned short)c1[5]);
      a[6] += p * b2f((unsigned short)c1[6]);
      a[7] += p * b2f((unsigned short)c1[7]);
      c0 = n0;
      c1 = n1;
    }
  }

  float mo = __shfl_xor(m, 32);
  float M = fmaxf(m, mo);
  float r = __expf(m - M);
  den *= r;
#pragma unroll
  for (int i = 0; i < 8; ++i) a[i] *= r;
  den += __shfl_xor(den, 32);
#pragma unroll
  for (int i = 0; i < 8; ++i) a[i] += __shfl_xor(a[i], 32);

  if (half == 0) {
    float inv = 1.f / (den > 0.f ? den : 1.f);
    u16x8 o;
#pragma unroll
    for (int i = 0; i < 8; ++i) o[i] = f2bu(a[i] * inv);
    *(u16x8*)((unsigned short*)attn + (size_t)n * DD + doff) = o;
  }
}

// ---------------------------------------------------------------- readout
__global__ __launch_bounds__(256) void k_gmean(
    const float* __restrict__ h, const int* __restrict__ gb,
    float* __restrict__ gsum) {
  int g = blockIdx.x, s = blockIdx.y;
  int t = threadIdx.x;
  int r0 = gb[g], r1 = gb[g + 1];
  int len = r1 - r0;
  int per = (len + RSPLITS - 1) / RSPLITS;
  int a = r0 + s * per;
  int b = min(r1, a + per);
  if (a >= b) return;
  float acc = 0.f;
  for (int r = a; r < b; ++r) acc += h[(size_t)r * DD + t];
  atomicAdd(&gsum[g * DD + t], acc);
}

__global__ void k_final(const float* __restrict__ gsum, const int* __restrict__ gb,
                        float* __restrict__ out) {
  int g = blockIdx.x, t = threadIdx.x;
  int len = gb[g + 1] - gb[g];
  out[g * DD + t] = gsum[g * DD + t] / (len > 0 ? (float)len : 1.f);
}

// ---------------------------------------------------------------- launch
extern "C" void kernel_launch(void* const* d_in, const int* in_sizes, int n_in,
                              void* d_out, int out_size, void* d_ws, size_t ws_size,
                              hipStream_t stream) {
  const float* feat = (const float*)d_in[0];
  const float* lap  = (const float*)d_in[1];
  const float* sign = (const float*)d_in[2];
  const int* srcs   = (const int*)d_in[3];
  const int* dsts   = (const int*)d_in[4];
  const int* gids   = (const int*)d_in[5];
  const float* Wh   = (const float*)d_in[6];
  const float* bh   = (const float*)d_in[7];
  const float* Wlp  = (const float*)d_in[8];
  const float* blp  = (const float*)d_in[9];
  const float* Wq   = (const float*)d_in[10];
  const float* Wk   = (const float*)d_in[11];
  const float* Wv   = (const float*)d_in[12];
  const float* Wo   = (const float*)d_in[13];
  const float* bo   = (const float*)d_in[14];
  const float* g1   = (const float*)d_in[15];
  const float* b1   = (const float*)d_in[16];
  const float* W1   = (const float*)d_in[17];
  const float* c1   = (const float*)d_in[18];
  const float* W2   = (const float*)d_in[19];
  const float* c2   = (const float*)d_in[20];
  const float* g2   = (const float*)d_in[21];
  const float* b2   = (const float*)d_in[22];

  char* base = (char*)d_ws;
  size_t off = 0;
  auto take = [&](size_t bytes) -> void* {
    void* p = base + off;
    off += (bytes + 255) & ~(size_t)255;
    return p;
  };
  float* h      = (float*)take((size_t)NN * DD * 4);
  float* tmp    = (float*)take((size_t)NN * DD * 4);
  __hip_bfloat16* hb  = (__hip_bfloat16*)take((size_t)NN * DD * 2);
  __hip_bfloat16* Qb  = (__hip_bfloat16*)take((size_t)NN * DD * 2);
  __hip_bfloat16* kvb = (__hip_bfloat16*)take((size_t)NN * 2 * DD * 2);
  __hip_bfloat16* t1b = (__hip_bfloat16*)take((size_t)NN * DFF * 2);
  __hip_bfloat16* Wqt = (__hip_bfloat16*)take((size_t)LLAYERS * DD * DD * 2);
  __hip_bfloat16* Wkt = (__hip_bfloat16*)take((size_t)LLAYERS * DD * DD * 2);
  __hip_bfloat16* Wvt = (__hip_bfloat16*)take((size_t)LLAYERS * DD * DD * 2);
  __hip_bfloat16* Wot = (__hip_bfloat16*)take((size_t)LLAYERS * DD * DD * 2);
  __hip_bfloat16* W1t = (__hip_bfloat16*)take((size_t)LLAYERS * DD * DFF * 2);
  __hip_bfloat16* W2t = (__hip_bfloat16*)take((size_t)LLAYERS * DFF * DD * 2);
  int* deg     = (int*)take((size_t)NN * 4);
  int* ex      = (int*)take((size_t)NN * 4);
  int* bsum    = (int*)take(256 * 4);
  int* boff    = (int*)take(256 * 4);
  int* indptr  = (int*)take((size_t)(NN + 1) * 4);
  int* cursor  = (int*)take((size_t)NN * 4);
  int* csr_src = (int*)take((size_t)EE * 4);
  int* gb      = (int*)take((size_t)(GG + 1) * 4);
  float* gsum  = (float*)take((size_t)GG * DD * 4);
  __hip_bfloat16* attnb = Qb;  // Q dead after k_attn (own-row read-before-write)

  const int NB = (NN + 255) / 256;

  // all weight transposes in one dispatch
  k_wt_all<<<dim3(DFF / 32, DFF / 32, 12), 256, 0, stream>>>(
      Wq, Wk, Wv, Wo, W1, W2, Wqt, Wkt, Wvt, Wot, W1t, W2t);

  // CSR by dst + graph bounds
  hipMemsetAsync(deg, 0, (size_t)NN * 4, stream);
  k_hist<<<(EE + 255) / 256, 256, 0, stream>>>(dsts, deg, EE);
  k_scan_block<<<NB, 256, 0, stream>>>(deg, ex, bsum, NN);
  k_scan_top<<<1, 256, 0, stream>>>(bsum, boff, NB);
  k_finish_indptr<<<NB, 256, 0, stream>>>(ex, boff, indptr, cursor, NN, EE);
  k_fill<<<(EE + 255) / 256, 256, 0, stream>>>(dsts, srcs, cursor, csr_src, EE);
  k_bounds<<<NB, 256, 0, stream>>>(gids, gb, NN);

  // embedding
  k_embed<<<NN, 256, 0, stream>>>(feat, lap, sign, Wh, bh, Wlp, blp, h, hb);

  const int MB = (NN + 127) / 128;   // 157
  dim3 gQKV(MB, DD / 128, 3);
  dim3 gD(MB, DD / 128, 1);
  dim3 gF(MB, DFF / 128, 1);

  for (int l = 0; l < LLAYERS; ++l) {
    const __hip_bfloat16* Wqt_l = Wqt + (size_t)l * DD * DD;
    const __hip_bfloat16* Wkt_l = Wkt + (size_t)l * DD * DD;
    const __hip_bfloat16* Wvt_l = Wvt + (size_t)l * DD * DD;
    const __hip_bfloat16* Wot_l = Wot + (size_t)l * DD * DD;
    const __hip_bfloat16* W1t_l = W1t + (size_t)l * DD * DFF;
    const __hip_bfloat16* W2t_l = W2t + (size_t)l * DFF * DD;
    const float* bo_l = bo + (size_t)l * DD;
    const float* g1_l = g1 + (size_t)l * DD;
    const float* b1_l = b1 + (size_t)l * DD;
    const float* c1_l = c1 + (size_t)l * DFF;
    const float* c2_l = c2 + (size_t)l * DD;
    const float* g2_l = g2 + (size_t)l * DD;
    const float* b2_l = b2 + (size_t)l * DD;

    // Q -> Qb; K,V -> kvb dim-interleaved
    gemm_mfma<false, false, true, false><<<gQKV, 256, 0, stream>>>(
        hb, Wqt_l, Wkt_l, Wvt_l, nullptr, Qb, kvb, NN, DD, DD);

    k_attn<<<(NN + 3) / 4, 256, 0, stream>>>(indptr, csr_src, Qb, kvb, attnb);

    // attn @ Wo + bias -> tmp (f32), then residual+LN
    gemm_mfma<true, false, false, true><<<gD, 256, 0, stream>>>(
        attnb, Wot_l, Wot_l, Wot_l, bo_l, tmp, tmp, NN, DD, DD);
    k_ln<<<NN / 4, 256, 0, stream>>>(h, tmp, g1_l, b1_l, hb, NN);

    // FFN
    gemm_mfma<true, true, false, false><<<gF, 256, 0, stream>>>(
        hb, W1t_l, W1t_l, W1t_l, c1_l, t1b, t1b, NN, DD, DFF);
    gemm_mfma<true, false, false, true><<<gD, 256, 0, stream>>>(
        t1b, W2t_l, W2t_l, W2t_l, c2_l, tmp, tmp, NN, DFF, DD);
    k_ln<<<NN / 4, 256, 0, stream>>>(h, tmp, g2_l, b2_l, hb, NN);
  }

  hipMemsetAsync(gsum, 0, (size_t)GG * DD * 4, stream);
  k_gmean<<<dim3(GG, RSPLITS), 256, 0, stream>>>(h, gb, gsum);
  k_final<<<GG, 256, 0, stream>>>(gsum, gb, (float*)d_out);
}

// Round 13
// 464.008 us; speedup vs baseline: 1.0488x; 1.0000x over previous
//
#include <hip/hip_runtime.h>
#include <hip/hip_bf16.h>

#define NN   20000
#define EE   320000
#define GG   16
#define DD   256
#define HH   8
#define DHH  32
#define LLAYERS 2
#define DFF  512
#define DIN  32
#define DLAP 16
#define RSPLITS 16

typedef __attribute__((ext_vector_type(8))) short bf16x8;
typedef __attribute__((ext_vector_type(8))) unsigned short u16x8;
typedef __attribute__((ext_vector_type(4))) float f32x4;

__device__ __forceinline__ void gld_lds16(const void* g, void* l) {
  __builtin_amdgcn_global_load_lds((const __attribute__((address_space(1))) uint32_t*)g,
                                   (__attribute__((address_space(3))) uint32_t*)l, 16, 0, 0);
}

__device__ __forceinline__ float b2f(unsigned short s) {
  union { unsigned int i; float f; } u;
  u.i = ((unsigned int)s) << 16;
  return u.f;
}

__device__ __forceinline__ unsigned short f2bu(float f) {
  __hip_bfloat16 b = __float2bfloat16(f);
  return *(unsigned short*)&b;
}

// ---------------------------------------------------------------- embed (f32 + bf16 shadow)
__global__ __launch_bounds__(256) void k_embed(
    const float* __restrict__ feat, const float* __restrict__ lap,
    const float* __restrict__ sign, const float* __restrict__ Wh,
    const float* __restrict__ bh, const float* __restrict__ Wlp,
    const float* __restrict__ blp, float* __restrict__ h,
    __hip_bfloat16* __restrict__ hb) {
  int n = blockIdx.x;
  int d = threadIdx.x;
  float acc = bh[d] + blp[d];
  const float* frow = feat + (size_t)n * DIN;
  const float* lrow = lap + (size_t)n * DLAP;
#pragma unroll
  for (int k = 0; k < DIN; ++k) acc += frow[k] * Wh[k * DD + d];
#pragma unroll
  for (int k = 0; k < DLAP; ++k) acc += (lrow[k] * sign[k]) * Wlp[k * DD + d];
  h[(size_t)n * DD + d] = acc;
  hb[(size_t)n * DD + d] = __float2bfloat16(acc);
}

// ---------------------------------------------------------------- all weight transposes in one dispatch
__global__ __launch_bounds__(256) void k_wt_all(
    const float* __restrict__ Wq, const float* __restrict__ Wk,
    const float* __restrict__ Wv, const float* __restrict__ Wo,
    const float* __restrict__ W1, const float* __restrict__ W2,
    __hip_bfloat16* __restrict__ Wqt, __hip_bfloat16* __restrict__ Wkt,
    __hip_bfloat16* __restrict__ Wvt, __hip_bfloat16* __restrict__ Wot,
    __hip_bfloat16* __restrict__ W1t, __hip_bfloat16* __restrict__ W2t) {
  __shared__ float tile[32][33];
  int z = blockIdx.z;
  const float* in;
  __hip_bfloat16* out;
  int K, N, l;
  if (z < 8) {
    int widx = z >> 1;
    l = z & 1;
    K = DD; N = DD;
    in = (widx == 0) ? Wq : (widx == 1) ? Wk : (widx == 2) ? Wv : Wo;
    out = (widx == 0) ? Wqt : (widx == 1) ? Wkt : (widx == 2) ? Wvt : Wot;
  } else if (z < 10) {
    l = z - 8; K = DD; N = DFF; in = W1; out = W1t;
  } else {
    l = z - 10; K = DFF; N = DD; in = W2; out = W2t;
  }
  int bx = blockIdx.x, by = blockIdx.y;
  if (bx * 32 >= N || by * 32 >= K) return;
  const float* inl = in + (size_t)l * K * N;
  __hip_bfloat16* outl = out + (size_t)l * N * K;
  int tx = threadIdx.x & 31, ty = threadIdx.x >> 5;
#pragma unroll
  for (int i = 0; i < 32; i += 8)
    tile[ty + i][tx] = inl[(size_t)(by * 32 + ty + i) * N + bx * 32 + tx];
  __syncthreads();
#pragma unroll
  for (int i = 0; i < 32; i += 8)
    outl[(size_t)(bx * 32 + ty + i) * K + by * 32 + tx] = __float2bfloat16(tile[tx][ty + i]);
}

// ---------------------------------------------------------------- MFMA bf16 GEMM (128x128, BK=32)
// KVPACK: z=0 -> Q into C0; z=1 -> K dim-interleaved into C1; z=2 -> V dim-interleaved into C1.
// OUTF32: C0 is float* (full-precision output for LN input).
template <bool BIAS, bool RELU, bool KVPACK, bool OUTF32>
__global__ __launch_bounds__(256) void gemm_mfma(
    const __hip_bfloat16* __restrict__ A,
    const __hip_bfloat16* __restrict__ Bt0, const __hip_bfloat16* __restrict__ Bt1,
    const __hip_bfloat16* __restrict__ Bt2,
    const float* __restrict__ bias,
    void* __restrict__ C0, void* __restrict__ C1,
    int M, int K, int ldc0) {
  const __hip_bfloat16* Bt = (blockIdx.z == 0) ? Bt0 : (blockIdx.z == 1) ? Bt1 : Bt2;
  void* Cout = (blockIdx.z == 0) ? C0 : C1;
  const int vo = (blockIdx.z == 2) ? 4 : 0;

  __shared__ short lA[2][4][128][8];
  __shared__ short lB[2][4][128][8];

  const int t = threadIdx.x;
  const int lane = t & 63, w = t >> 6;
  const int bm = blockIdx.x * 128, bn = blockIdx.y * 128;
  const int wr = w >> 1, wc = w & 1;
  const int fr = lane & 15, fg = lane >> 4;

  f32x4 acc[4][4] = {};

  auto stage = [&](int buf, int kt) {
    const int k0 = kt * 32;
#pragma unroll
    for (int it = 0; it < 2; ++it) {
      const int cbase = it * 256 + w * 64;
      const int c = cbase + lane;
      const int g = c >> 7, r = c & 127;
      int arow = bm + r;
      if (arow >= M) arow = M - 1;
      gld_lds16(A + (size_t)arow * K + k0 + g * 8,
                (short*)lA + ((size_t)buf * 512 + cbase) * 8);
      gld_lds16(Bt + (size_t)(bn + r) * K + k0 + g * 8,
                (short*)lB + ((size_t)buf * 512 + cbase) * 8);
    }
  };

  const int nt = K >> 5;
  stage(0, 0);
  for (int kt = 0; kt < nt; ++kt) {
    const int buf = kt & 1;
    __syncthreads();
    if (kt + 1 < nt) stage(buf ^ 1, kt + 1);
    bf16x8 af[4], bfr[4];
#pragma unroll
    for (int i = 0; i < 4; ++i)
      af[i] = *(const bf16x8*)&lA[buf][fg][wr * 64 + i * 16 + fr][0];
#pragma unroll
    for (int j = 0; j < 4; ++j)
      bfr[j] = *(const bf16x8*)&lB[buf][fg][wc * 64 + j * 16 + fr][0];
#pragma unroll
    for (int i = 0; i < 4; ++i)
#pragma unroll
      for (int j = 0; j < 4; ++j)
        acc[i][j] = __builtin_amdgcn_mfma_f32_16x16x32_bf16(af[i], bfr[j], acc[i][j], 0, 0, 0);
  }

#pragma unroll
  for (int i = 0; i < 4; ++i) {
    const int row0 = bm + wr * 64 + i * 16 + fg * 4;
#pragma unroll
    for (int j = 0; j < 4; ++j) {
      const int col = bn + wc * 64 + j * 16 + fr;
      float bv = BIAS ? bias[col] : 0.f;
#pragma unroll
      for (int r = 0; r < 4; ++r) {
        const int row = row0 + r;
        if (row >= M) continue;
        float v = acc[i][j][r] + bv;
        if (RELU) v = fmaxf(v, 0.f);
        if (KVPACK && blockIdx.z != 0) {
          ((__hip_bfloat16*)Cout)[(size_t)row * (2 * DD) + ((col >> 2) << 3) + vo + (col & 3)] =
              __float2bfloat16(v);
        } else if (OUTF32) {
          ((float*)Cout)[(size_t)row * ldc0 + col] = v;
        } else {
          ((__hip_bfloat16*)Cout)[(size_t)row * ldc0 + col] = __float2bfloat16(v);
        }
      }
    }
  }
}

// ---------------------------------------------------------------- residual + LayerNorm (in-place on h, bf16 shadow)
__global__ __launch_bounds__(256) void k_ln(
    float* __restrict__ h, const float* __restrict__ add,
    const float* __restrict__ g, const float* __restrict__ b,
    __hip_bfloat16* __restrict__ hb, int n) {
  int row = blockIdx.x * 4 + (threadIdx.x >> 6);
  int lane = threadIdx.x & 63;
  if (row >= n) return;
  const size_t base = (size_t)row * DD;
  float x[4];
  float s = 0.f;
#pragma unroll
  for (int j = 0; j < 4; ++j) {
    int d = lane + j * 64;
    x[j] = h[base + d] + add[base + d];
    s += x[j];
  }
#pragma unroll
  for (int o = 32; o > 0; o >>= 1) s += __shfl_xor(s, o, 64);
  float mean = s * (1.f / 256.f);
  float vs = 0.f;
#pragma unroll
  for (int j = 0; j < 4; ++j) {
    float d = x[j] - mean;
    vs += d * d;
  }
#pragma unroll
  for (int o = 32; o > 0; o >>= 1) vs += __shfl_xor(vs, o, 64);
  float rs = rsqrtf(vs * (1.f / 256.f) + 1e-5f);
#pragma unroll
  for (int j = 0; j < 4; ++j) {
    int d = lane + j * 64;
    float v = g[d] * ((x[j] - mean) * rs) + b[d];
    h[base + d] = v;
    hb[base + d] = __float2bfloat16(v);
  }
}

// ---------------------------------------------------------------- CSR build
__global__ void k_hist(const int* __restrict__ dst, int* __restrict__ deg, int n) {
  int i = blockIdx.x * blockDim.x + threadIdx.x;
  if (i < n) atomicAdd(&deg[dst[i]], 1);
}

__global__ __launch_bounds__(256) void k_scan_block(
    const int* __restrict__ in, int* __restrict__ ex, int* __restrict__ bsum, int n) {
  __shared__ int sm[256];
  int t = threadIdx.x;
  int i = blockIdx.x * 256 + t;
  int v = (i < n) ? in[i] : 0;
  sm[t] = v;
  __syncthreads();
  for (int o = 1; o < 256; o <<= 1) {
    int x = (t >= o) ? sm[t - o] : 0;
    __syncthreads();
    sm[t] += x;
    __syncthreads();
  }
  if (i < n) ex[i] = sm[t] - v;
  if (t == 255) bsum[blockIdx.x] = sm[255];
}

__global__ __launch_bounds__(256) void k_scan_top(
    const int* __restrict__ bsum, int* __restrict__ boff, int nb) {
  __shared__ int sm[256];
  int t = threadIdx.x;
  int v = (t < nb) ? bsum[t] : 0;
  sm[t] = v;
  __syncthreads();
  for (int o = 1; o < 256; o <<= 1) {
    int x = (t >= o) ? sm[t - o] : 0;
    __syncthreads();
    sm[t] += x;
    __syncthreads();
  }
  if (t < nb) boff[t] = sm[t] - v;
}

__global__ void k_finish_indptr(const int* __restrict__ ex, const int* __restrict__ boff,
                                int* __restrict__ indptr, int* __restrict__ cursor,
                                int n, int total) {
  int i = blockIdx.x * 256 + threadIdx.x;
  if (i < n) {
    int v = ex[i] + boff[i >> 8];
    indptr[i] = v;
    cursor[i] = v;
  }
  if (i == 0) indptr[n] = total;
}

__global__ void k_fill(const int* __restrict__ dst, const int* __restrict__ src,
                       int* __restrict__ cursor, int* __restrict__ csr_src, int n) {
  int i = blockIdx.x * blockDim.x + threadIdx.x;
  if (i < n) {
    int pos = atomicAdd(&cursor[dst[i]], 1);
    csr_src[pos] = src[i];
  }
}

// graph boundaries from sorted gids
__global__ void k_bounds(const int* __restrict__ gid, int* __restrict__ gb, int n) {
  int i = blockIdx.x * blockDim.x + threadIdx.x;
  if (i >= n) return;
  int g = gid[i];
  if (i == 0) {
    for (int x = 0; x <= g; ++x) gb[x] = 0;
  } else {
    int pg = gid[i - 1];
    for (int x = pg + 1; x <= g; ++x) gb[x] = i;
  }
  if (i == n - 1) {
    for (int x = g + 1; x <= GG; ++x) gb[x] = n;
  }
}

// ---------------------------------------------------------------- fused attention: half-wave per edge, depth-2 pipeline
// one wave per node; lanes 0-31 take even CSR slots, 32-63 odd; sub-lane owns 8 dims.
// KV dim-interleaved in kvb[N][512]: granule g: K dims at g*8+0..3, V dims at g*8+4..7.
__global__ __launch_bounds__(256) void k_attn(
    const int* __restrict__ indptr, const int* __restrict__ csr_src,
    const __hip_bfloat16* __restrict__ Q, const __hip_bfloat16* __restrict__ kvb,
    __hip_bfloat16* __restrict__ attn) {
  int n = blockIdx.x * 4 + (threadIdx.x >> 6);
  if (n >= NN) return;
  int lane = threadIdx.x & 63;
  int half = lane >> 5;
  int sl = lane & 31;
  int doff = sl * 8;
  int s0 = indptr[n], s1 = indptr[n + 1];

  u16x8 qv = *(const u16x8*)((const unsigned short*)Q + (size_t)n * DD + doff);
  float q[8];
#pragma unroll
  for (int i = 0; i < 8; ++i) q[i] = b2f((unsigned short)qv[i]);

  const unsigned short* kvp = (const unsigned short*)kvb;

  float m = 0.f, den = 0.f;
  float a[8] = {};

  auto process = [&](u16x8 c0, u16x8 c1) {
    float dot = q[0] * b2f((unsigned short)c0[0]) + q[1] * b2f((unsigned short)c0[1]) +
                q[2] * b2f((unsigned short)c0[2]) + q[3] * b2f((unsigned short)c0[3]) +
                q[4] * b2f((unsigned short)c1[0]) + q[5] * b2f((unsigned short)c1[1]) +
                q[6] * b2f((unsigned short)c1[2]) + q[7] * b2f((unsigned short)c1[3]);
    dot += __shfl_xor(dot, 1);
    dot += __shfl_xor(dot, 2);  // 4-lane head group complete
    float x = fminf(fmaxf(dot * 0.17677669529663687f, -5.f), 5.f);
    float s = __expf(x);
    if (s - m > 8.f) {  // rare deferred-max rescale
      float r = __expf(m - s);
      den *= r;
#pragma unroll
      for (int i = 0; i < 8; ++i) a[i] *= r;
      m = s;
    }
    float p = __expf(s - m);  // bounded by e^8
    den += p;
    a[0] += p * b2f((unsigned short)c0[4]);
    a[1] += p * b2f((unsigned short)c0[5]);
    a[2] += p * b2f((unsigned short)c0[6]);
    a[3] += p * b2f((unsigned short)c0[7]);
    a[4] += p * b2f((unsigned short)c1[4]);
    a[5] += p * b2f((unsigned short)c1[5]);
    a[6] += p * b2f((unsigned short)c1[6]);
    a[7] += p * b2f((unsigned short)c1[7]);
  };

  int j = s0 + half;
  if (j < s1) {
    // preload slots j and j+2 (clamped)
    const unsigned short* r0 = kvp + (size_t)csr_src[j] * (2 * DD) + sl * 16;
    u16x8 A0 = *(const u16x8*)r0, A1 = *(const u16x8*)(r0 + 8);
    int j2 = (j + 2 < s1) ? j + 2 : s1 - 1;
    const unsigned short* r1 = kvp + (size_t)csr_src[j2] * (2 * DD) + sl * 16;
    u16x8 B0 = *(const u16x8*)r1, B1 = *(const u16x8*)(r1 + 8);
    for (; j < s1; j += 4) {
      // prefetch slots j+4 and j+6 (clamped; harmless duplicates near tail)
      int i0 = (j + 4 < s1) ? j + 4 : s1 - 1;
      int i1 = (j + 6 < s1) ? j + 6 : s1 - 1;
      const unsigned short* p0 = kvp + (size_t)csr_src[i0] * (2 * DD) + sl * 16;
      const unsigned short* p1 = kvp + (size_t)csr_src[i1] * (2 * DD) + sl * 16;
      u16x8 N0 = *(const u16x8*)p0, N1 = *(const u16x8*)(p0 + 8);
      u16x8 N2 = *(const u16x8*)p1, N3 = *(const u16x8*)(p1 + 8);

      process(A0, A1);
      if (j + 2 < s1) process(B0, B1);

      A0 = N0; A1 = N1; B0 = N2; B1 = N3;
    }
  }

  // merge the two halves (exact): rescale both to common max, then add partner's partials
  float mo = __shfl_xor(m, 32);
  float M = fmaxf(m, mo);
  float r = __expf(m - M);
  den *= r;
#pragma unroll
  for (int i = 0; i < 8; ++i) a[i] *= r;
  den += __shfl_xor(den, 32);
#pragma unroll
  for (int i = 0; i < 8; ++i) a[i] += __shfl_xor(a[i], 32);

  if (half == 0) {
    float inv = 1.f / (den > 0.f ? den : 1.f);
    u16x8 o;
#pragma unroll
    for (int i = 0; i < 8; ++i) o[i] = f2bu(a[i] * inv);
    *(u16x8*)((unsigned short*)attn + (size_t)n * DD + doff) = o;
  }
}

// ---------------------------------------------------------------- readout
__global__ __launch_bounds__(256) void k_gmean(
    const float* __restrict__ h, const int* __restrict__ gb,
    float* __restrict__ gsum) {
  int g = blockIdx.x, s = blockIdx.y;
  int t = threadIdx.x;
  int r0 = gb[g], r1 = gb[g + 1];
  int len = r1 - r0;
  int per = (len + RSPLITS - 1) / RSPLITS;
  int a = r0 + s * per;
  int b = min(r1, a + per);
  if (a >= b) return;
  float acc = 0.f;
  for (int r = a; r < b; ++r) acc += h[(size_t)r * DD + t];
  atomicAdd(&gsum[g * DD + t], acc);
}

__global__ void k_final(const float* __restrict__ gsum, const int* __restrict__ gb,
                        float* __restrict__ out) {
  int g = blockIdx.x, t = threadIdx.x;
  int len = gb[g + 1] - gb[g];
  out[g * DD + t] = gsum[g * DD + t] / (len > 0 ? (float)len : 1.f);
}

// ---------------------------------------------------------------- launch
extern "C" void kernel_launch(void* const* d_in, const int* in_sizes, int n_in,
                              void* d_out, int out_size, void* d_ws, size_t ws_size,
                              hipStream_t stream) {
  const float* feat = (const float*)d_in[0];
  const float* lap  = (const float*)d_in[1];
  const float* sign = (const float*)d_in[2];
  const int* srcs   = (const int*)d_in[3];
  const int* dsts   = (const int*)d_in[4];
  const int* gids   = (const int*)d_in[5];
  const float* Wh   = (const float*)d_in[6];
  const float* bh   = (const float*)d_in[7];
  const float* Wlp  = (const float*)d_in[8];
  const float* blp  = (const float*)d_in[9];
  const float* Wq   = (const float*)d_in[10];
  const float* Wk   = (const float*)d_in[11];
  const float* Wv   = (const float*)d_in[12];
  const float* Wo   = (const float*)d_in[13];
  const float* bo   = (const float*)d_in[14];
  const float* g1   = (const float*)d_in[15];
  const float* b1   = (const float*)d_in[16];
  const float* W1   = (const float*)d_in[17];
  const float* c1   = (const float*)d_in[18];
  const float* W2   = (const float*)d_in[19];
  const float* c2   = (const float*)d_in[20];
  const float* g2   = (const float*)d_in[21];
  const float* b2   = (const float*)d_in[22];

  char* base = (char*)d_ws;
  size_t off = 0;
  auto take = [&](size_t bytes) -> void* {
    void* p = base + off;
    off += (bytes + 255) & ~(size_t)255;
    return p;
  };
  float* h      = (float*)take((size_t)NN * DD * 4);
  float* tmp    = (float*)take((size_t)NN * DD * 4);
  __hip_bfloat16* hb  = (__hip_bfloat16*)take((size_t)NN * DD * 2);
  __hip_bfloat16* Qb  = (__hip_bfloat16*)take((size_t)NN * DD * 2);
  __hip_bfloat16* kvb = (__hip_bfloat16*)take((size_t)NN * 2 * DD * 2);
  __hip_bfloat16* t1b = (__hip_bfloat16*)take((size_t)NN * DFF * 2);
  __hip_bfloat16* Wqt = (__hip_bfloat16*)take((size_t)LLAYERS * DD * DD * 2);
  __hip_bfloat16* Wkt = (__hip_bfloat16*)take((size_t)LLAYERS * DD * DD * 2);
  __hip_bfloat16* Wvt = (__hip_bfloat16*)take((size_t)LLAYERS * DD * DD * 2);
  __hip_bfloat16* Wot = (__hip_bfloat16*)take((size_t)LLAYERS * DD * DD * 2);
  __hip_bfloat16* W1t = (__hip_bfloat16*)take((size_t)LLAYERS * DD * DFF * 2);
  __hip_bfloat16* W2t = (__hip_bfloat16*)take((size_t)LLAYERS * DFF * DD * 2);
  int* deg     = (int*)take((size_t)NN * 4);
  int* ex      = (int*)take((size_t)NN * 4);
  int* bsum    = (int*)take(256 * 4);
  int* boff    = (int*)take(256 * 4);
  int* indptr  = (int*)take((size_t)(NN + 1) * 4);
  int* cursor  = (int*)take((size_t)NN * 4);
  int* csr_src = (int*)take((size_t)EE * 4);
  int* gb      = (int*)take((size_t)(GG + 1) * 4);
  float* gsum  = (float*)take((size_t)GG * DD * 4);
  __hip_bfloat16* attnb = Qb;  // Q dead after k_attn (own-row read-before-write)

  const int NB = (NN + 255) / 256;

  // all weight transposes in one dispatch
  k_wt_all<<<dim3(DFF / 32, DFF / 32, 12), 256, 0, stream>>>(
      Wq, Wk, Wv, Wo, W1, W2, Wqt, Wkt, Wvt, Wot, W1t, W2t);

  // CSR by dst + graph bounds
  hipMemsetAsync(deg, 0, (size_t)NN * 4, stream);
  k_hist<<<(EE + 255) / 256, 256, 0, stream>>>(dsts, deg, EE);
  k_scan_block<<<NB, 256, 0, stream>>>(deg, ex, bsum, NN);
  k_scan_top<<<1, 256, 0, stream>>>(bsum, boff, NB);
  k_finish_indptr<<<NB, 256, 0, stream>>>(ex, boff, indptr, cursor, NN, EE);
  k_fill<<<(EE + 255) / 256, 256, 0, stream>>>(dsts, srcs, cursor, csr_src, EE);
  k_bounds<<<NB, 256, 0, stream>>>(gids, gb, NN);

  // embedding
  k_embed<<<NN, 256, 0, stream>>>(feat, lap, sign, Wh, bh, Wlp, blp, h, hb);

  const int MB = (NN + 127) / 128;   // 157
  dim3 gQKV(MB, DD / 128, 3);
  dim3 gD(MB, DD / 128, 1);
  dim3 gF(MB, DFF / 128, 1);

  for (int l = 0; l < LLAYERS; ++l) {
    const __hip_bfloat16* Wqt_l = Wqt + (size_t)l * DD * DD;
    const __hip_bfloat16* Wkt_l = Wkt + (size_t)l * DD * DD;
    const __hip_bfloat16* Wvt_l = Wvt + (size_t)l * DD * DD;
    const __hip_bfloat16* Wot_l = Wot + (size_t)l * DD * DD;
    const __hip_bfloat16* W1t_l = W1t + (size_t)l * DD * DFF;
    const __hip_bfloat16* W2t_l = W2t + (size_t)l * DFF * DD;
    const float* bo_l = bo + (size_t)l * DD;
    const float* g1_l = g1 + (size_t)l * DD;
    const float* b1_l = b1 + (size_t)l * DD;
    const float* c1_l = c1 + (size_t)l * DFF;
    const float* c2_l = c2 + (size_t)l * DD;
    const float* g2_l = g2 + (size_t)l * DD;
    const float* b2_l = b2 + (size_t)l * DD;

    // Q -> Qb; K,V -> kvb dim-interleaved
    gemm_mfma<false, false, true, false><<<gQKV, 256, 0, stream>>>(
        hb, Wqt_l, Wkt_l, Wvt_l, nullptr, Qb, kvb, NN, DD, DD);

    k_attn<<<(NN + 3) / 4, 256, 0, stream>>>(indptr, csr_src, Qb, kvb, attnb);

    // attn @ Wo + bias -> tmp (f32), then residual+LN
    gemm_mfma<true, false, false, true><<<gD, 256, 0, stream>>>(
        attnb, Wot_l, Wot_l, Wot_l, bo_l, tmp, tmp, NN, DD, DD);
    k_ln<<<NN / 4, 256, 0, stream>>>(h, tmp, g1_l, b1_l, hb, NN);

    // FFN
    gemm_mfma<true, true, false, false><<<gF, 256, 0, stream>>>(
        hb, W1t_l, W1t_l, W1t_l, c1_l, t1b, t1b, NN, DD, DFF);
    gemm_mfma<true, false, false, true><<<gD, 256, 0, stream>>>(
        t1b, W2t_l, W2t_l, W2t_l, c2_l, tmp, tmp, NN, DFF, DD);
    k_ln<<<NN / 4, 256, 0, stream>>>(h, tmp, g2_l, b2_l, hb, NN);
  }

  hipMemsetAsync(gsum, 0, (size_t)GG * DD * 4, stream);
  k_gmean<<<dim3(GG, RSPLITS), 256, 0, stream>>>(h, gb, gsum);
  k_final<<<GG, 256, 0, stream>>>(gsum, gb, (float*)d_out);
}

// Round 14
// 452.693 us; speedup vs baseline: 1.0750x; 1.0250x over previous
//
#include <hip/hip_runtime.h>
#include <hip/hip_bf16.h>

#define NN   20000
#define EE   320000
#define GG   16
#define DD   256
#define HH   8
#define DHH  32
#define LLAYERS 2
#define DFF  512
#define DIN  32
#define DLAP 16
#define RSPLITS 16

typedef __attribute__((ext_vector_type(8))) short bf16x8;
typedef __attribute__((ext_vector_type(8))) unsigned short u16x8;
typedef __attribute__((ext_vector_type(4))) float f32x4;

__device__ __forceinline__ void gld_lds16(const void* g, void* l) {
  __builtin_amdgcn_global_load_lds((const __attribute__((address_space(1))) uint32_t*)g,
                                   (__attribute__((address_space(3))) uint32_t*)l, 16, 0, 0);
}

__device__ __forceinline__ float b2f(unsigned short s) {
  union { unsigned int i; float f; } u;
  u.i = ((unsigned int)s) << 16;
  return u.f;
}

__device__ __forceinline__ unsigned short f2bu(float f) {
  __hip_bfloat16 b = __float2bfloat16(f);
  return *(unsigned short*)&b;
}

// ---------------------------------------------------------------- embed (grid-stride, f32 + bf16 shadow)
__global__ __launch_bounds__(256) void k_embed(
    const float* __restrict__ feat, const float* __restrict__ lap,
    const float* __restrict__ sign, const float* __restrict__ Wh,
    const float* __restrict__ bh, const float* __restrict__ Wlp,
    const float* __restrict__ blp, float* __restrict__ h,
    __hip_bfloat16* __restrict__ hb) {
  int d = threadIdx.x;
  const float bias = bh[d] + blp[d];
  for (int n = blockIdx.x; n < NN; n += gridDim.x) {
    float acc = bias;
    const float* frow = feat + (size_t)n * DIN;
    const float* lrow = lap + (size_t)n * DLAP;
#pragma unroll
    for (int k = 0; k < DIN; ++k) acc += frow[k] * Wh[k * DD + d];
#pragma unroll
    for (int k = 0; k < DLAP; ++k) acc += (lrow[k] * sign[k]) * Wlp[k * DD + d];
    h[(size_t)n * DD + d] = acc;
    hb[(size_t)n * DD + d] = __float2bfloat16(acc);
  }
}

// ---------------------------------------------------------------- all weight transposes in one dispatch
__global__ __launch_bounds__(256) void k_wt_all(
    const float* __restrict__ Wq, const float* __restrict__ Wk,
    const float* __restrict__ Wv, const float* __restrict__ Wo,
    const float* __restrict__ W1, const float* __restrict__ W2,
    __hip_bfloat16* __restrict__ Wqt, __hip_bfloat16* __restrict__ Wkt,
    __hip_bfloat16* __restrict__ Wvt, __hip_bfloat16* __restrict__ Wot,
    __hip_bfloat16* __restrict__ W1t, __hip_bfloat16* __restrict__ W2t) {
  __shared__ float tile[32][33];
  int z = blockIdx.z;
  const float* in;
  __hip_bfloat16* out;
  int K, N, l;
  if (z < 8) {
    int widx = z >> 1;
    l = z & 1;
    K = DD; N = DD;
    in = (widx == 0) ? Wq : (widx == 1) ? Wk : (widx == 2) ? Wv : Wo;
    out = (widx == 0) ? Wqt : (widx == 1) ? Wkt : (widx == 2) ? Wvt : Wot;
  } else if (z < 10) {
    l = z - 8; K = DD; N = DFF; in = W1; out = W1t;
  } else {
    l = z - 10; K = DFF; N = DD; in = W2; out = W2t;
  }
  int bx = blockIdx.x, by = blockIdx.y;
  if (bx * 32 >= N || by * 32 >= K) return;
  const float* inl = in + (size_t)l * K * N;
  __hip_bfloat16* outl = out + (size_t)l * N * K;
  int tx = threadIdx.x & 31, ty = threadIdx.x >> 5;
#pragma unroll
  for (int i = 0; i < 32; i += 8)
    tile[ty + i][tx] = inl[(size_t)(by * 32 + ty + i) * N + bx * 32 + tx];
  __syncthreads();
#pragma unroll
  for (int i = 0; i < 32; i += 8)
    outl[(size_t)(bx * 32 + ty + i) * K + by * 32 + tx] = __float2bfloat16(tile[tx][ty + i]);
}

// ---------------------------------------------------------------- MFMA bf16 GEMM (128x128, BK=32)
// KVPACK: z=0 -> Q into C0; z=1 -> K dim-interleaved into C1; z=2 -> V dim-interleaved into C1.
// OUTF32: C0 is float* (full-precision output for LN input).
template <bool BIAS, bool RELU, bool KVPACK, bool OUTF32>
__global__ __launch_bounds__(256) void gemm_mfma(
    const __hip_bfloat16* __restrict__ A,
    const __hip_bfloat16* __restrict__ Bt0, const __hip_bfloat16* __restrict__ Bt1,
    const __hip_bfloat16* __restrict__ Bt2,
    const float* __restrict__ bias,
    void* __restrict__ C0, void* __restrict__ C1,
    int M, int K, int ldc0) {
  const __hip_bfloat16* Bt = (blockIdx.z == 0) ? Bt0 : (blockIdx.z == 1) ? Bt1 : Bt2;
  void* Cout = (blockIdx.z == 0) ? C0 : C1;
  const int vo = (blockIdx.z == 2) ? 4 : 0;

  __shared__ short lA[2][4][128][8];
  __shared__ short lB[2][4][128][8];

  const int t = threadIdx.x;
  const int lane = t & 63, w = t >> 6;
  const int bm = blockIdx.x * 128, bn = blockIdx.y * 128;
  const int wr = w >> 1, wc = w & 1;
  const int fr = lane & 15, fg = lane >> 4;

  f32x4 acc[4][4] = {};

  auto stage = [&](int buf, int kt) {
    const int k0 = kt * 32;
#pragma unroll
    for (int it = 0; it < 2; ++it) {
      const int cbase = it * 256 + w * 64;
      const int c = cbase + lane;
      const int g = c >> 7, r = c & 127;
      int arow = bm + r;
      if (arow >= M) arow = M - 1;
      gld_lds16(A + (size_t)arow * K + k0 + g * 8,
                (short*)lA + ((size_t)buf * 512 + cbase) * 8);
      gld_lds16(Bt + (size_t)(bn + r) * K + k0 + g * 8,
                (short*)lB + ((size_t)buf * 512 + cbase) * 8);
    }
  };

  const int nt = K >> 5;
  stage(0, 0);
  for (int kt = 0; kt < nt; ++kt) {
    const int buf = kt & 1;
    __syncthreads();
    if (kt + 1 < nt) stage(buf ^ 1, kt + 1);
    bf16x8 af[4], bfr[4];
#pragma unroll
    for (int i = 0; i < 4; ++i)
      af[i] = *(const bf16x8*)&lA[buf][fg][wr * 64 + i * 16 + fr][0];
#pragma unroll
    for (int j = 0; j < 4; ++j)
      bfr[j] = *(const bf16x8*)&lB[buf][fg][wc * 64 + j * 16 + fr][0];
#pragma unroll
    for (int i = 0; i < 4; ++i)
#pragma unroll
      for (int j = 0; j < 4; ++j)
        acc[i][j] = __builtin_amdgcn_mfma_f32_16x16x32_bf16(af[i], bfr[j], acc[i][j], 0, 0, 0);
  }

#pragma unroll
  for (int i = 0; i < 4; ++i) {
    const int row0 = bm + wr * 64 + i * 16 + fg * 4;
#pragma unroll
    for (int j = 0; j < 4; ++j) {
      const int col = bn + wc * 64 + j * 16 + fr;
      float bv = BIAS ? bias[col] : 0.f;
#pragma unroll
      for (int r = 0; r < 4; ++r) {
        const int row = row0 + r;
        if (row >= M) continue;
        float v = acc[i][j][r] + bv;
        if (RELU) v = fmaxf(v, 0.f);
        if (KVPACK && blockIdx.z != 0) {
          ((__hip_bfloat16*)Cout)[(size_t)row * (2 * DD) + ((col >> 2) << 3) + vo + (col & 3)] =
              __float2bfloat16(v);
        } else if (OUTF32) {
          ((float*)Cout)[(size_t)row * ldc0 + col] = v;
        } else {
          ((__hip_bfloat16*)Cout)[(size_t)row * ldc0 + col] = __float2bfloat16(v);
        }
      }
    }
  }
}

// ---------------------------------------------------------------- residual + LayerNorm (in-place on h, bf16 shadow)
__global__ __launch_bounds__(256) void k_ln(
    float* __restrict__ h, const float* __restrict__ add,
    const float* __restrict__ g, const float* __restrict__ b,
    __hip_bfloat16* __restrict__ hb, int n) {
  int row = blockIdx.x * 4 + (threadIdx.x >> 6);
  int lane = threadIdx.x & 63;
  if (row >= n) return;
  const size_t base = (size_t)row * DD;
  float x[4];
  float s = 0.f;
#pragma unroll
  for (int j = 0; j < 4; ++j) {
    int d = lane + j * 64;
    x[j] = h[base + d] + add[base + d];
    s += x[j];
  }
#pragma unroll
  for (int o = 32; o > 0; o >>= 1) s += __shfl_xor(s, o, 64);
  float mean = s * (1.f / 256.f);
  float vs = 0.f;
#pragma unroll
  for (int j = 0; j < 4; ++j) {
    float d = x[j] - mean;
    vs += d * d;
  }
#pragma unroll
  for (int o = 32; o > 0; o >>= 1) vs += __shfl_xor(vs, o, 64);
  float rs = rsqrtf(vs * (1.f / 256.f) + 1e-5f);
#pragma unroll
  for (int j = 0; j < 4; ++j) {
    int d = lane + j * 64;
    float v = g[d] * ((x[j] - mean) * rs) + b[d];
    h[base + d] = v;
    hb[base + d] = __float2bfloat16(v);
  }
}

// ---------------------------------------------------------------- CSR build
__global__ void k_hist(const int* __restrict__ dst, int* __restrict__ deg, int n) {
  int i = blockIdx.x * blockDim.x + threadIdx.x;
  if (i < n) atomicAdd(&deg[dst[i]], 1);
}

__global__ __launch_bounds__(256) void k_scan_block(
    const int* __restrict__ in, int* __restrict__ ex, int* __restrict__ bsum, int n) {
  __shared__ int sm[256];
  int t = threadIdx.x;
  int i = blockIdx.x * 256 + t;
  int v = (i < n) ? in[i] : 0;
  sm[t] = v;
  __syncthreads();
  for (int o = 1; o < 256; o <<= 1) {
    int x = (t >= o) ? sm[t - o] : 0;
    __syncthreads();
    sm[t] += x;
    __syncthreads();
  }
  if (i < n) ex[i] = sm[t] - v;
  if (t == 255) bsum[blockIdx.x] = sm[255];
}

// finish: inline exclusive prefix of bsum (wave-uniform loop -> scalar loads)
__global__ void k_finish_indptr(const int* __restrict__ ex, const int* __restrict__ bsum,
                                int* __restrict__ indptr, int* __restrict__ cursor,
                                int n, int total) {
  int i = blockIdx.x * 256 + threadIdx.x;
  if (i < n) {
    int blk = i >> 8;  // uniform within block
    int off = 0;
    for (int x = 0; x < blk; ++x) off += bsum[x];
    int v = ex[i] + off;
    indptr[i] = v;
    cursor[i] = v;
  }
  if (i == 0) indptr[n] = total;
}

__global__ void k_fill(const int* __restrict__ dst, const int* __restrict__ src,
                       int* __restrict__ cursor, int* __restrict__ csr_src, int n) {
  int i = blockIdx.x * blockDim.x + threadIdx.x;
  if (i < n) {
    int pos = atomicAdd(&cursor[dst[i]], 1);
    csr_src[pos] = src[i];
  }
}

// graph boundaries from sorted gids
__global__ void k_bounds(const int* __restrict__ gid, int* __restrict__ gb, int n) {
  int i = blockIdx.x * blockDim.x + threadIdx.x;
  if (i >= n) return;
  int g = gid[i];
  if (i == 0) {
    for (int x = 0; x <= g; ++x) gb[x] = 0;
  } else {
    int pg = gid[i - 1];
    for (int x = pg + 1; x <= g; ++x) gb[x] = i;
  }
  if (i == n - 1) {
    for (int x = g + 1; x <= GG; ++x) gb[x] = n;
  }
}

// ---------------------------------------------------------------- fused attention: persistent grid-stride waves
// one wave per node (strided); lanes 0-31 even CSR slots, 32-63 odd; sub-lane owns 8 dims.
// KV dim-interleaved in kvb[N][512]: granule g: K dims at g*8+0..3, V dims at g*8+4..7.
__global__ __launch_bounds__(256) void k_attn(
    const int* __restrict__ indptr, const int* __restrict__ csr_src,
    const __hip_bfloat16* __restrict__ Q, const __hip_bfloat16* __restrict__ kvb,
    __hip_bfloat16* __restrict__ attn) {
  const int wid0 = blockIdx.x * 4 + (threadIdx.x >> 6);
  const int NW = gridDim.x * 4;
  const int lane = threadIdx.x & 63;
  const int half = lane >> 5;
  const int sl = lane & 31;
  const int doff = sl * 8;
  const unsigned short* kvp = (const unsigned short*)kvb;

  for (int n = wid0; n < NN; n += NW) {
    int s0 = indptr[n], s1 = indptr[n + 1];
    unsigned short* outp = (unsigned short*)attn + (size_t)n * DD + doff;

    u16x8 qv = *(const u16x8*)((const unsigned short*)Q + (size_t)n * DD + doff);
    float q[8];
#pragma unroll
    for (int i = 0; i < 8; ++i) q[i] = b2f((unsigned short)qv[i]);

    float m = 0.f, den = 0.f;
    float a[8] = {};

    int j = s0 + half;
    if (j < s1) {
      const unsigned short* row = kvp + (size_t)csr_src[j] * (2 * DD) + sl * 16;
      u16x8 c0 = *(const u16x8*)row;
      u16x8 c1 = *(const u16x8*)(row + 8);
      for (; j < s1; j += 2) {
        int jn = (j + 2 < s1) ? j + 2 : j;
        const unsigned short* rown = kvp + (size_t)csr_src[jn] * (2 * DD) + sl * 16;
        u16x8 n0 = *(const u16x8*)rown;
        u16x8 n1 = *(const u16x8*)(rown + 8);

        float dot = q[0] * b2f((unsigned short)c0[0]) + q[1] * b2f((unsigned short)c0[1]) +
                    q[2] * b2f((unsigned short)c0[2]) + q[3] * b2f((unsigned short)c0[3]) +
                    q[4] * b2f((unsigned short)c1[0]) + q[5] * b2f((unsigned short)c1[1]) +
                    q[6] * b2f((unsigned short)c1[2]) + q[7] * b2f((unsigned short)c1[3]);
        dot += __shfl_xor(dot, 1);
        dot += __shfl_xor(dot, 2);  // 4-lane head group complete
        float x = fminf(fmaxf(dot * 0.17677669529663687f, -5.f), 5.f);
        float s = __expf(x);
        if (s - m > 8.f) {  // rare deferred-max rescale
          float r = __expf(m - s);
          den *= r;
#pragma unroll
          for (int i = 0; i < 8; ++i) a[i] *= r;
          m = s;
        }
        float p = __expf(s - m);  // bounded by e^8
        den += p;
        a[0] += p * b2f((unsigned short)c0[4]);
        a[1] += p * b2f((unsigned short)c0[5]);
        a[2] += p * b2f((unsigned short)c0[6]);
        a[3] += p * b2f((unsigned short)c0[7]);
        a[4] += p * b2f((unsigned short)c1[4]);
        a[5] += p * b2f((unsigned short)c1[5]);
        a[6] += p * b2f((unsigned short)c1[6]);
        a[7] += p * b2f((unsigned short)c1[7]);
        c0 = n0;
        c1 = n1;
      }
    }

    // merge the two halves (exact)
    float mo = __shfl_xor(m, 32);
    float M = fmaxf(m, mo);
    float r = __expf(m - M);
    den *= r;
#pragma unroll
    for (int i = 0; i < 8; ++i) a[i] *= r;
    den += __shfl_xor(den, 32);
#pragma unroll
    for (int i = 0; i < 8; ++i) a[i] += __shfl_xor(a[i], 32);

    if (half == 0) {
      float inv = 1.f / (den > 0.f ? den : 1.f);
      u16x8 o;
#pragma unroll
      for (int i = 0; i < 8; ++i) o[i] = f2bu(a[i] * inv);
      *(u16x8*)outp = o;
    }
  }
}

// ---------------------------------------------------------------- readout
__global__ __launch_bounds__(256) void k_gmean(
    const float* __restrict__ h, const int* __restrict__ gb,
    float* __restrict__ gsum) {
  int g = blockIdx.x, s = blockIdx.y;
  int t = threadIdx.x;
  int r0 = gb[g], r1 = gb[g + 1];
  int len = r1 - r0;
  int per = (len + RSPLITS - 1) / RSPLITS;
  int a = r0 + s * per;
  int b = min(r1, a + per);
  if (a >= b) return;
  float acc = 0.f;
  for (int r = a; r < b; ++r) acc += h[(size_t)r * DD + t];
  atomicAdd(&gsum[g * DD + t], acc);
}

__global__ void k_final(const float* __restrict__ gsum, const int* __restrict__ gb,
                        float* __restrict__ out) {
  int g = blockIdx.x, t = threadIdx.x;
  int len = gb[g + 1] - gb[g];
  out[g * DD + t] = gsum[g * DD + t] / (len > 0 ? (float)len : 1.f);
}

// ---------------------------------------------------------------- launch
extern "C" void kernel_launch(void* const* d_in, const int* in_sizes, int n_in,
                              void* d_out, int out_size, void* d_ws, size_t ws_size,
                              hipStream_t stream) {
  const float* feat = (const float*)d_in[0];
  const float* lap  = (const float*)d_in[1];
  const float* sign = (const float*)d_in[2];
  const int* srcs   = (const int*)d_in[3];
  const int* dsts   = (const int*)d_in[4];
  const int* gids   = (const int*)d_in[5];
  const float* Wh   = (const float*)d_in[6];
  const float* bh   = (const float*)d_in[7];
  const float* Wlp  = (const float*)d_in[8];
  const float* blp  = (const float*)d_in[9];
  const float* Wq   = (const float*)d_in[10];
  const float* Wk   = (const float*)d_in[11];
  const float* Wv   = (const float*)d_in[12];
  const float* Wo   = (const float*)d_in[13];
  const float* bo   = (const float*)d_in[14];
  const float* g1   = (const float*)d_in[15];
  const float* b1   = (const float*)d_in[16];
  const float* W1   = (const float*)d_in[17];
  const float* c1   = (const float*)d_in[18];
  const float* W2   = (const float*)d_in[19];
  const float* c2   = (const float*)d_in[20];
  const float* g2   = (const float*)d_in[21];
  const float* b2   = (const float*)d_in[22];

  char* base = (char*)d_ws;
  size_t off = 0;
  auto take = [&](size_t bytes) -> void* {
    void* p = base + off;
    off += (bytes + 255) & ~(size_t)255;
    return p;
  };
  float* h      = (float*)take((size_t)NN * DD * 4);
  float* tmp    = (float*)take((size_t)NN * DD * 4);
  __hip_bfloat16* hb  = (__hip_bfloat16*)take((size_t)NN * DD * 2);
  __hip_bfloat16* Qb  = (__hip_bfloat16*)take((size_t)NN * DD * 2);
  __hip_bfloat16* kvb = (__hip_bfloat16*)take((size_t)NN * 2 * DD * 2);
  __hip_bfloat16* t1b = (__hip_bfloat16*)take((size_t)NN * DFF * 2);
  __hip_bfloat16* Wqt = (__hip_bfloat16*)take((size_t)LLAYERS * DD * DD * 2);
  __hip_bfloat16* Wkt = (__hip_bfloat16*)take((size_t)LLAYERS * DD * DD * 2);
  __hip_bfloat16* Wvt = (__hip_bfloat16*)take((size_t)LLAYERS * DD * DD * 2);
  __hip_bfloat16* Wot = (__hip_bfloat16*)take((size_t)LLAYERS * DD * DD * 2);
  __hip_bfloat16* W1t = (__hip_bfloat16*)take((size_t)LLAYERS * DD * DFF * 2);
  __hip_bfloat16* W2t = (__hip_bfloat16*)take((size_t)LLAYERS * DFF * DD * 2);
  int* deg     = (int*)take((size_t)NN * 4);
  int* ex      = (int*)take((size_t)NN * 4);
  int* bsum    = (int*)take(256 * 4);
  int* indptr  = (int*)take((size_t)(NN + 1) * 4);
  int* cursor  = (int*)take((size_t)NN * 4);
  int* csr_src = (int*)take((size_t)EE * 4);
  int* gb      = (int*)take((size_t)(GG + 1) * 4);
  float* gsum  = (float*)take((size_t)GG * DD * 4);
  __hip_bfloat16* attnb = Qb;  // Q dead after k_attn (own-row read-before-write)

  const int NB = (NN + 255) / 256;

  // all weight transposes in one dispatch
  k_wt_all<<<dim3(DFF / 32, DFF / 32, 12), 256, 0, stream>>>(
      Wq, Wk, Wv, Wo, W1, W2, Wqt, Wkt, Wvt, Wot, W1t, W2t);

  // CSR by dst + graph bounds
  hipMemsetAsync(deg, 0, (size_t)NN * 4, stream);
  k_hist<<<(EE + 255) / 256, 256, 0, stream>>>(dsts, deg, EE);
  k_scan_block<<<NB, 256, 0, stream>>>(deg, ex, bsum, NN);
  k_finish_indptr<<<NB, 256, 0, stream>>>(ex, bsum, indptr, cursor, NN, EE);
  k_fill<<<(EE + 255) / 256, 256, 0, stream>>>(dsts, srcs, cursor, csr_src, EE);
  k_bounds<<<NB, 256, 0, stream>>>(gids, gb, NN);

  // embedding (grid-stride)
  k_embed<<<2048, 256, 0, stream>>>(feat, lap, sign, Wh, bh, Wlp, blp, h, hb);

  const int MB = (NN + 127) / 128;   // 157
  dim3 gQKV(MB, DD / 128, 3);
  dim3 gD(MB, DD / 128, 1);
  dim3 gF(MB, DFF / 128, 1);

  for (int l = 0; l < LLAYERS; ++l) {
    const __hip_bfloat16* Wqt_l = Wqt + (size_t)l * DD * DD;
    const __hip_bfloat16* Wkt_l = Wkt + (size_t)l * DD * DD;
    const __hip_bfloat16* Wvt_l = Wvt + (size_t)l * DD * DD;
    const __hip_bfloat16* Wot_l = Wot + (size_t)l * DD * DD;
    const __hip_bfloat16* W1t_l = W1t + (size_t)l * DD * DFF;
    const __hip_bfloat16* W2t_l = W2t + (size_t)l * DFF * DD;
    const float* bo_l = bo + (size_t)l * DD;
    const float* g1_l = g1 + (size_t)l * DD;
    const float* b1_l = b1 + (size_t)l * DD;
    const float* c1_l = c1 + (size_t)l * DFF;
    const float* c2_l = c2 + (size_t)l * DD;
    const float* g2_l = g2 + (size_t)l * DD;
    const float* b2_l = b2 + (size_t)l * DD;

    // Q -> Qb; K,V -> kvb dim-interleaved
    gemm_mfma<false, false, true, false><<<gQKV, 256, 0, stream>>>(
        hb, Wqt_l, Wkt_l, Wvt_l, nullptr, Qb, kvb, NN, DD, DD);

    k_attn<<<2048, 256, 0, stream>>>(indptr, csr_src, Qb, kvb, attnb);

    // attn @ Wo + bias -> tmp (f32), then residual+LN
    gemm_mfma<true, false, false, true><<<gD, 256, 0, stream>>>(
        attnb, Wot_l, Wot_l, Wot_l, bo_l, tmp, tmp, NN, DD, DD);
    k_ln<<<NN / 4, 256, 0, stream>>>(h, tmp, g1_l, b1_l, hb, NN);

    // FFN
    gemm_mfma<true, true, false, false><<<gF, 256, 0, stream>>>(
        hb, W1t_l, W1t_l, W1t_l, c1_l, t1b, t1b, NN, DD, DFF);
    gemm_mfma<true, false, false, true><<<gD, 256, 0, stream>>>(
        t1b, W2t_l, W2t_l, W2t_l, c2_l, tmp, tmp, NN, DFF, DD);
    k_ln<<<NN / 4, 256, 0, stream>>>(h, tmp, g2_l, b2_l, hb, NN);
  }

  hipMemsetAsync(gsum, 0, (size_t)GG * DD * 4, stream);
  k_gmean<<<dim3(GG, RSPLITS), 256, 0, stream>>>(h, gb, gsum);
  k_final<<<GG, 256, 0, stream>>>(gsum, gb, (float*)d_out);
}

// Round 15
// 432.764 us; speedup vs baseline: 1.1246x; 1.0461x over previous
//
#include <hip/hip_runtime.h>
#include <hip/hip_bf16.h>

#define NN   20000
#define EE   320000
#define GG   16
#define DD   256
#define HH   8
#define DHH  32
#define LLAYERS 2
#define DFF  512
#define DIN  32
#define DLAP 16
#define RSPLITS 16

typedef __attribute__((ext_vector_type(8))) short bf16x8;
typedef __attribute__((ext_vector_type(8))) unsigned short u16x8;
typedef __attribute__((ext_vector_type(4))) float f32x4;

__device__ __forceinline__ void gld_lds16(const void* g, void* l) {
  __builtin_amdgcn_global_load_lds((const __attribute__((address_space(1))) uint32_t*)g,
                                   (__attribute__((address_space(3))) uint32_t*)l, 16, 0, 0);
}

__device__ __forceinline__ float b2f(unsigned short s) {
  union { unsigned int i; float f; } u;
  u.i = ((unsigned int)s) << 16;
  return u.f;
}

__device__ __forceinline__ unsigned short f2bu(float f) {
  __hip_bfloat16 b = __float2bfloat16(f);
  return *(unsigned short*)&b;
}

// ---------------------------------------------------------------- embed (grid-stride, f32 + bf16 shadow)
__global__ __launch_bounds__(256) void k_embed(
    const float* __restrict__ feat, const float* __restrict__ lap,
    const float* __restrict__ sign, const float* __restrict__ Wh,
    const float* __restrict__ bh, const float* __restrict__ Wlp,
    const float* __restrict__ blp, float* __restrict__ h,
    __hip_bfloat16* __restrict__ hb) {
  int d = threadIdx.x;
  const float bias = bh[d] + blp[d];
  for (int n = blockIdx.x; n < NN; n += gridDim.x) {
    float acc = bias;
    const float* frow = feat + (size_t)n * DIN;
    const float* lrow = lap + (size_t)n * DLAP;
#pragma unroll
    for (int k = 0; k < DIN; ++k) acc += frow[k] * Wh[k * DD + d];
#pragma unroll
    for (int k = 0; k < DLAP; ++k) acc += (lrow[k] * sign[k]) * Wlp[k * DD + d];
    h[(size_t)n * DD + d] = acc;
    hb[(size_t)n * DD + d] = __float2bfloat16(acc);
  }
}

// ---------------------------------------------------------------- all weight transposes in one dispatch
__global__ __launch_bounds__(256) void k_wt_all(
    const float* __restrict__ Wq, const float* __restrict__ Wk,
    const float* __restrict__ Wv, const float* __restrict__ Wo,
    const float* __restrict__ W1, const float* __restrict__ W2,
    __hip_bfloat16* __restrict__ Wqt, __hip_bfloat16* __restrict__ Wkt,
    __hip_bfloat16* __restrict__ Wvt, __hip_bfloat16* __restrict__ Wot,
    __hip_bfloat16* __restrict__ W1t, __hip_bfloat16* __restrict__ W2t) {
  __shared__ float tile[32][33];
  int z = blockIdx.z;
  const float* in;
  __hip_bfloat16* out;
  int K, N, l;
  if (z < 8) {
    int widx = z >> 1;
    l = z & 1;
    K = DD; N = DD;
    in = (widx == 0) ? Wq : (widx == 1) ? Wk : (widx == 2) ? Wv : Wo;
    out = (widx == 0) ? Wqt : (widx == 1) ? Wkt : (widx == 2) ? Wvt : Wot;
  } else if (z < 10) {
    l = z - 8; K = DD; N = DFF; in = W1; out = W1t;
  } else {
    l = z - 10; K = DFF; N = DD; in = W2; out = W2t;
  }
  int bx = blockIdx.x, by = blockIdx.y;
  if (bx * 32 >= N || by * 32 >= K) return;
  const float* inl = in + (size_t)l * K * N;
  __hip_bfloat16* outl = out + (size_t)l * N * K;
  int tx = threadIdx.x & 31, ty = threadIdx.x >> 5;
#pragma unroll
  for (int i = 0; i < 32; i += 8)
    tile[ty + i][tx] = inl[(size_t)(by * 32 + ty + i) * N + bx * 32 + tx];
  __syncthreads();
#pragma unroll
  for (int i = 0; i < 32; i += 8)
    outl[(size_t)(bx * 32 + ty + i) * K + by * 32 + tx] = __float2bfloat16(tile[tx][ty + i]);
}

// ---------------------------------------------------------------- MFMA bf16 GEMM (BMx128, BK=32), BM in {128, 64}
// KVPACK: z=0 -> Q into C0; z=1 -> K dim-interleaved into C1; z=2 -> V dim-interleaved into C1.
// OUTF32: C0 is float* (full-precision output for LN input).
template <int BM, bool BIAS, bool RELU, bool KVPACK, bool OUTF32>
__global__ __launch_bounds__(256) void gemm_mfma(
    const __hip_bfloat16* __restrict__ A,
    const __hip_bfloat16* __restrict__ Bt0, const __hip_bfloat16* __restrict__ Bt1,
    const __hip_bfloat16* __restrict__ Bt2,
    const float* __restrict__ bias,
    void* __restrict__ C0, void* __restrict__ C1,
    int M, int K, int ldc0) {
  const __hip_bfloat16* Bt = (blockIdx.z == 0) ? Bt0 : (blockIdx.z == 1) ? Bt1 : Bt2;
  void* Cout = (blockIdx.z == 0) ? C0 : C1;
  const int vo = (blockIdx.z == 2) ? 4 : 0;

  constexpr int RI = BM / 32;  // 16-row frags per wave (wave covers BM/2 rows)
  __shared__ short lA[2][4][BM][8];
  __shared__ short lB[2][4][128][8];

  const int t = threadIdx.x;
  const int lane = t & 63, w = t >> 6;
  const int bm = blockIdx.x * BM, bn = blockIdx.y * 128;
  const int wrow = (w >> 1) * (BM / 2), wc = w & 1;
  const int fr = lane & 15, fg = lane >> 4;

  f32x4 acc[RI][4] = {};

  auto stage = [&](int buf, int kt) {
    const int k0 = kt * 32;
#pragma unroll
    for (int it = 0; it < BM / 64; ++it) {  // A: BM*4 chunks
      const int cbase = it * 256 + w * 64;
      const int c = cbase + lane;
      const int g = c / BM, r = c % BM;
      int arow = bm + r;
      if (arow >= M) arow = M - 1;
      gld_lds16(A + (size_t)arow * K + k0 + g * 8,
                (short*)lA + ((size_t)buf * (4 * BM) + cbase) * 8);
    }
#pragma unroll
    for (int it = 0; it < 2; ++it) {  // B: 512 chunks
      const int cbase = it * 256 + w * 64;
      const int c = cbase + lane;
      const int g = c >> 7, r = c & 127;
      gld_lds16(Bt + (size_t)(bn + r) * K + k0 + g * 8,
                (short*)lB + ((size_t)buf * 512 + cbase) * 8);
    }
  };

  const int nt = K >> 5;
  stage(0, 0);
  for (int kt = 0; kt < nt; ++kt) {
    const int buf = kt & 1;
    __syncthreads();
    if (kt + 1 < nt) stage(buf ^ 1, kt + 1);
    bf16x8 af[RI], bfr[4];
#pragma unroll
    for (int i = 0; i < RI; ++i)
      af[i] = *(const bf16x8*)&lA[buf][fg][wrow + i * 16 + fr][0];
#pragma unroll
    for (int j = 0; j < 4; ++j)
      bfr[j] = *(const bf16x8*)&lB[buf][fg][wc * 64 + j * 16 + fr][0];
#pragma unroll
    for (int i = 0; i < RI; ++i)
#pragma unroll
      for (int j = 0; j < 4; ++j)
        acc[i][j] = __builtin_amdgcn_mfma_f32_16x16x32_bf16(af[i], bfr[j], acc[i][j], 0, 0, 0);
  }

#pragma unroll
  for (int i = 0; i < RI; ++i) {
    const int row0 = bm + wrow + i * 16 + fg * 4;
#pragma unroll
    for (int j = 0; j < 4; ++j) {
      const int col = bn + wc * 64 + j * 16 + fr;
      float bv = BIAS ? bias[col] : 0.f;
#pragma unroll
      for (int r = 0; r < 4; ++r) {
        const int row = row0 + r;
        if (row >= M) continue;
        float v = acc[i][j][r] + bv;
        if (RELU) v = fmaxf(v, 0.f);
        if (KVPACK && blockIdx.z != 0) {
          ((__hip_bfloat16*)Cout)[(size_t)row * (2 * DD) + ((col >> 2) << 3) + vo + (col & 3)] =
              __float2bfloat16(v);
        } else if (OUTF32) {
          ((float*)Cout)[(size_t)row * ldc0 + col] = v;
        } else {
          ((__hip_bfloat16*)Cout)[(size_t)row * ldc0 + col] = __float2bfloat16(v);
        }
      }
    }
  }
}

// ---------------------------------------------------------------- residual + LayerNorm (in-place on h, bf16 shadow)
__global__ __launch_bounds__(256) void k_ln(
    float* __restrict__ h, const float* __restrict__ add,
    const float* __restrict__ g, const float* __restrict__ b,
    __hip_bfloat16* __restrict__ hb, int n) {
  int row = blockIdx.x * 4 + (threadIdx.x >> 6);
  int lane = threadIdx.x & 63;
  if (row >= n) return;
  const size_t base = (size_t)row * DD;
  float x[4];
  float s = 0.f;
#pragma unroll
  for (int j = 0; j < 4; ++j) {
    int d = lane + j * 64;
    x[j] = h[base + d] + add[base + d];
    s += x[j];
  }
#pragma unroll
  for (int o = 32; o > 0; o >>= 1) s += __shfl_xor(s, o, 64);
  float mean = s * (1.f / 256.f);
  float vs = 0.f;
#pragma unroll
  for (int j = 0; j < 4; ++j) {
    float d = x[j] - mean;
    vs += d * d;
  }
#pragma unroll
  for (int o = 32; o > 0; o >>= 1) vs += __shfl_xor(vs, o, 64);
  float rs = rsqrtf(vs * (1.f / 256.f) + 1e-5f);
#pragma unroll
  for (int j = 0; j < 4; ++j) {
    int d = lane + j * 64;
    float v = g[d] * ((x[j] - mean) * rs) + b[d];
    h[base + d] = v;
    hb[base + d] = __float2bfloat16(v);
  }
}

// ---------------------------------------------------------------- CSR build
__global__ void k_hist(const int* __restrict__ dst, int* __restrict__ deg, int n) {
  int i = blockIdx.x * blockDim.x + threadIdx.x;
  if (i < n) atomicAdd(&deg[dst[i]], 1);
}

__global__ __launch_bounds__(256) void k_scan_block(
    const int* __restrict__ in, int* __restrict__ ex, int* __restrict__ bsum, int n) {
  __shared__ int sm[256];
  int t = threadIdx.x;
  int i = blockIdx.x * 256 + t;
  int v = (i < n) ? in[i] : 0;
  sm[t] = v;
  __syncthreads();
  for (int o = 1; o < 256; o <<= 1) {
    int x = (t >= o) ? sm[t - o] : 0;
    __syncthreads();
    sm[t] += x;
    __syncthreads();
  }
  if (i < n) ex[i] = sm[t] - v;
  if (t == 255) bsum[blockIdx.x] = sm[255];
}

// finish: inline exclusive prefix of bsum (wave-uniform loop -> scalar loads)
__global__ void k_finish_indptr(const int* __restrict__ ex, const int* __restrict__ bsum,
                                int* __restrict__ indptr, int* __restrict__ cursor,
                                int n, int total) {
  int i = blockIdx.x * 256 + threadIdx.x;
  if (i < n) {
    int blk = i >> 8;  // uniform within block
    int off = 0;
    for (int x = 0; x < blk; ++x) off += bsum[x];
    int v = ex[i] + off;
    indptr[i] = v;
    cursor[i] = v;
  }
  if (i == 0) indptr[n] = total;
}

__global__ void k_fill(const int* __restrict__ dst, const int* __restrict__ src,
                       int* __restrict__ cursor, int* __restrict__ csr_src, int n) {
  int i = blockIdx.x * blockDim.x + threadIdx.x;
  if (i < n) {
    int pos = atomicAdd(&cursor[dst[i]], 1);
    csr_src[pos] = src[i];
  }
}

// graph boundaries from sorted gids
__global__ void k_bounds(const int* __restrict__ gid, int* __restrict__ gb, int n) {
  int i = blockIdx.x * blockDim.x + threadIdx.x;
  if (i >= n) return;
  int g = gid[i];
  if (i == 0) {
    for (int x = 0; x <= g; ++x) gb[x] = 0;
  } else {
    int pg = gid[i - 1];
    for (int x = pg + 1; x <= g; ++x) gb[x] = i;
  }
  if (i == n - 1) {
    for (int x = g + 1; x <= GG; ++x) gb[x] = n;
  }
}

// ---------------------------------------------------------------- fused attention: persistent grid-stride waves
__global__ __launch_bounds__(256) void k_attn(
    const int* __restrict__ indptr, const int* __restrict__ csr_src,
    const __hip_bfloat16* __restrict__ Q, const __hip_bfloat16* __restrict__ kvb,
    __hip_bfloat16* __restrict__ attn) {
  const int wid0 = blockIdx.x * 4 + (threadIdx.x >> 6);
  const int NW = gridDim.x * 4;
  const int lane = threadIdx.x & 63;
  const int half = lane >> 5;
  const int sl = lane & 31;
  const int doff = sl * 8;
  const unsigned short* kvp = (const unsigned short*)kvb;

  for (int n = wid0; n < NN; n += NW) {
    int s0 = indptr[n], s1 = indptr[n + 1];
    unsigned short* outp = (unsigned short*)attn + (size_t)n * DD + doff;

    u16x8 qv = *(const u16x8*)((const unsigned short*)Q + (size_t)n * DD + doff);
    float q[8];
#pragma unroll
    for (int i = 0; i < 8; ++i) q[i] = b2f((unsigned short)qv[i]);

    float m = 0.f, den = 0.f;
    float a[8] = {};

    int j = s0 + half;
    if (j < s1) {
      const unsigned short* row = kvp + (size_t)csr_src[j] * (2 * DD) + sl * 16;
      u16x8 c0 = *(const u16x8*)row;
      u16x8 c1 = *(const u16x8*)(row + 8);
      for (; j < s1; j += 2) {
        int jn = (j + 2 < s1) ? j + 2 : j;
        const unsigned short* rown = kvp + (size_t)csr_src[jn] * (2 * DD) + sl * 16;
        u16x8 n0 = *(const u16x8*)rown;
        u16x8 n1 = *(const u16x8*)(rown + 8);

        float dot = q[0] * b2f((unsigned short)c0[0]) + q[1] * b2f((unsigned short)c0[1]) +
                    q[2] * b2f((unsigned short)c0[2]) + q[3] * b2f((unsigned short)c0[3]) +
                    q[4] * b2f((unsigned short)c1[0]) + q[5] * b2f((unsigned short)c1[1]) +
                    q[6] * b2f((unsigned short)c1[2]) + q[7] * b2f((unsigned short)c1[3]);
        dot += __shfl_xor(dot, 1);
        dot += __shfl_xor(dot, 2);  // 4-lane head group complete
        float x = fminf(fmaxf(dot * 0.17677669529663687f, -5.f), 5.f);
        float s = __expf(x);
        if (s - m > 8.f) {  // rare deferred-max rescale
          float r = __expf(m - s);
          den *= r;
#pragma unroll
          for (int i = 0; i < 8; ++i) a[i] *= r;
          m = s;
        }
        float p = __expf(s - m);  // bounded by e^8
        den += p;
        a[0] += p * b2f((unsigned short)c0[4]);
        a[1] += p * b2f((unsigned short)c0[5]);
        a[2] += p * b2f((unsigned short)c0[6]);
        a[3] += p * b2f((unsigned short)c0[7]);
        a[4] += p * b2f((unsigned short)c1[4]);
        a[5] += p * b2f((unsigned short)c1[5]);
        a[6] += p * b2f((unsigned short)c1[6]);
        a[7] += p * b2f((unsigned short)c1[7]);
        c0 = n0;
        c1 = n1;
      }
    }

    // merge the two halves (exact)
    float mo = __shfl_xor(m, 32);
    float M = fmaxf(m, mo);
    float r = __expf(m - M);
    den *= r;
#pragma unroll
    for (int i = 0; i < 8; ++i) a[i] *= r;
    den += __shfl_xor(den, 32);
#pragma unroll
    for (int i = 0; i < 8; ++i) a[i] += __shfl_xor(a[i], 32);

    if (half == 0) {
      float inv = 1.f / (den > 0.f ? den : 1.f);
      u16x8 o;
#pragma unroll
      for (int i = 0; i < 8; ++i) o[i] = f2bu(a[i] * inv);
      *(u16x8*)outp = o;
    }
  }
}

// ---------------------------------------------------------------- readout
__global__ __launch_bounds__(256) void k_gmean(
    const float* __restrict__ h, const int* __restrict__ gb,
    float* __restrict__ gsum) {
  int g = blockIdx.x, s = blockIdx.y;
  int t = threadIdx.x;
  int r0 = gb[g], r1 = gb[g + 1];
  int len = r1 - r0;
  int per = (len + RSPLITS - 1) / RSPLITS;
  int a = r0 + s * per;
  int b = min(r1, a + per);
  if (a >= b) return;
  float acc = 0.f;
  for (int r = a; r < b; ++r) acc += h[(size_t)r * DD + t];
  atomicAdd(&gsum[g * DD + t], acc);
}

__global__ void k_final(const float* __restrict__ gsum, const int* __restrict__ gb,
                        float* __restrict__ out) {
  int g = blockIdx.x, t = threadIdx.x;
  int len = gb[g + 1] - gb[g];
  out[g * DD + t] = gsum[g * DD + t] / (len > 0 ? (float)len : 1.f);
}

// ---------------------------------------------------------------- launch
extern "C" void kernel_launch(void* const* d_in, const int* in_sizes, int n_in,
                              void* d_out, int out_size, void* d_ws, size_t ws_size,
                              hipStream_t stream) {
  const float* feat = (const float*)d_in[0];
  const float* lap  = (const float*)d_in[1];
  const float* sign = (const float*)d_in[2];
  const int* srcs   = (const int*)d_in[3];
  const int* dsts   = (const int*)d_in[4];
  const int* gids   = (const int*)d_in[5];
  const float* Wh   = (const float*)d_in[6];
  const float* bh   = (const float*)d_in[7];
  const float* Wlp  = (const float*)d_in[8];
  const float* blp  = (const float*)d_in[9];
  const float* Wq   = (const float*)d_in[10];
  const float* Wk   = (const float*)d_in[11];
  const float* Wv   = (const float*)d_in[12];
  const float* Wo   = (const float*)d_in[13];
  const float* bo   = (const float*)d_in[14];
  const float* g1   = (const float*)d_in[15];
  const float* b1   = (const float*)d_in[16];
  const float* W1   = (const float*)d_in[17];
  const float* c1   = (const float*)d_in[18];
  const float* W2   = (const float*)d_in[19];
  const float* c2   = (const float*)d_in[20];
  const float* g2   = (const float*)d_in[21];
  const float* b2   = (const float*)d_in[22];

  char* base = (char*)d_ws;
  size_t off = 0;
  auto take = [&](size_t bytes) -> void* {
    void* p = base + off;
    off += (bytes + 255) & ~(size_t)255;
    return p;
  };
  float* h      = (float*)take((size_t)NN * DD * 4);
  float* tmp    = (float*)take((size_t)NN * DD * 4);
  __hip_bfloat16* hb  = (__hip_bfloat16*)take((size_t)NN * DD * 2);
  __hip_bfloat16* Qb  = (__hip_bfloat16*)take((size_t)NN * DD * 2);
  __hip_bfloat16* kvb = (__hip_bfloat16*)take((size_t)NN * 2 * DD * 2);
  __hip_bfloat16* t1b = (__hip_bfloat16*)take((size_t)NN * DFF * 2);
  __hip_bfloat16* Wqt = (__hip_bfloat16*)take((size_t)LLAYERS * DD * DD * 2);
  __hip_bfloat16* Wkt = (__hip_bfloat16*)take((size_t)LLAYERS * DD * DD * 2);
  __hip_bfloat16* Wvt = (__hip_bfloat16*)take((size_t)LLAYERS * DD * DD * 2);
  __hip_bfloat16* Wot = (__hip_bfloat16*)take((size_t)LLAYERS * DD * DD * 2);
  __hip_bfloat16* W1t = (__hip_bfloat16*)take((size_t)LLAYERS * DD * DFF * 2);
  __hip_bfloat16* W2t = (__hip_bfloat16*)take((size_t)LLAYERS * DFF * DD * 2);
  int* deg     = (int*)take((size_t)NN * 4);
  int* ex      = (int*)take((size_t)NN * 4);
  int* bsum    = (int*)take(256 * 4);
  int* indptr  = (int*)take((size_t)(NN + 1) * 4);
  int* cursor  = (int*)take((size_t)NN * 4);
  int* csr_src = (int*)take((size_t)EE * 4);
  int* gb      = (int*)take((size_t)(GG + 1) * 4);
  float* gsum  = (float*)take((size_t)GG * DD * 4);
  __hip_bfloat16* attnb = Qb;  // Q dead after k_attn (own-row read-before-write)

  const int NB = (NN + 255) / 256;

  // all weight transposes in one dispatch
  k_wt_all<<<dim3(DFF / 32, DFF / 32, 12), 256, 0, stream>>>(
      Wq, Wk, Wv, Wo, W1, W2, Wqt, Wkt, Wvt, Wot, W1t, W2t);

  // CSR by dst + graph bounds
  hipMemsetAsync(deg, 0, (size_t)NN * 4, stream);
  k_hist<<<(EE + 255) / 256, 256, 0, stream>>>(dsts, deg, EE);
  k_scan_block<<<NB, 256, 0, stream>>>(deg, ex, bsum, NN);
  k_finish_indptr<<<NB, 256, 0, stream>>>(ex, bsum, indptr, cursor, NN, EE);
  k_fill<<<(EE + 255) / 256, 256, 0, stream>>>(dsts, srcs, cursor, csr_src, EE);
  k_bounds<<<NB, 256, 0, stream>>>(gids, gb, NN);

  // embedding (grid-stride)
  k_embed<<<2048, 256, 0, stream>>>(feat, lap, sign, Wh, bh, Wlp, blp, h, hb);

  const int MB128 = (NN + 127) / 128;  // 157
  const int MB64  = (NN + 63) / 64;    // 313
  dim3 gQKV(MB128, DD / 128, 3);
  dim3 gD64(MB64, DD / 128, 1);
  dim3 gF64(MB64, DFF / 128, 1);

  for (int l = 0; l < LLAYERS; ++l) {
    const __hip_bfloat16* Wqt_l = Wqt + (size_t)l * DD * DD;
    const __hip_bfloat16* Wkt_l = Wkt + (size_t)l * DD * DD;
    const __hip_bfloat16* Wvt_l = Wvt + (size_t)l * DD * DD;
    const __hip_bfloat16* Wot_l = Wot + (size_t)l * DD * DD;
    const __hip_bfloat16* W1t_l = W1t + (size_t)l * DD * DFF;
    const __hip_bfloat16* W2t_l = W2t + (size_t)l * DFF * DD;
    const float* bo_l = bo + (size_t)l * DD;
    const float* g1_l = g1 + (size_t)l * DD;
    const float* b1_l = b1 + (size_t)l * DD;
    const float* c1_l = c1 + (size_t)l * DFF;
    const float* c2_l = c2 + (size_t)l * DD;
    const float* g2_l = g2 + (size_t)l * DD;
    const float* b2_l = b2 + (size_t)l * DD;

    // Q -> Qb; K,V -> kvb dim-interleaved (BM=128, batched z)
    gemm_mfma<128, false, false, true, false><<<gQKV, 256, 0, stream>>>(
        hb, Wqt_l, Wkt_l, Wvt_l, nullptr, Qb, kvb, NN, DD, DD);

    k_attn<<<2048, 256, 0, stream>>>(indptr, csr_src, Qb, kvb, attnb);

    // attn @ Wo + bias -> tmp (f32), then residual+LN  (BM=64 for occupancy)
    gemm_mfma<64, true, false, false, true><<<gD64, 256, 0, stream>>>(
        attnb, Wot_l, Wot_l, Wot_l, bo_l, tmp, tmp, NN, DD, DD);
    k_ln<<<NN / 4, 256, 0, stream>>>(h, tmp, g1_l, b1_l, hb, NN);

    // FFN (BM=64)
    gemm_mfma<64, true, true, false, false><<<gF64, 256, 0, stream>>>(
        hb, W1t_l, W1t_l, W1t_l, c1_l, t1b, t1b, NN, DD, DFF);
    gemm_mfma<64, true, false, false, true><<<gD64, 256, 0, stream>>>(
        t1b, W2t_l, W2t_l, W2t_l, c2_l, tmp, tmp, NN, DFF, DD);
    k_ln<<<NN / 4, 256, 0, stream>>>(h, tmp, g2_l, b2_l, hb, NN);
  }

  hipMemsetAsync(gsum, 0, (size_t)GG * DD * 4, stream);
  k_gmean<<<dim3(GG, RSPLITS), 256, 0, stream>>>(h, gb, gsum);
  k_final<<<GG, 256, 0, stream>>>(gsum, gb, (float*)d_out);
}